// Round 2
// baseline (2117.599 us; speedup 1.0000x reference)
//
#include <hip/hip_runtime.h>
#include <math.h>

#define N_NODES 50000
#define K_DIM 128
#define R_REL 8
#define E_EDGES 500000
#define EPS 1e-8

// ---------- order-preserving float<->uint encoding for atomicMax ----------
__device__ __forceinline__ unsigned enc_f32(float f) {
  unsigned u = __float_as_uint(f);
  return (u & 0x80000000u) ? ~u : (u | 0x80000000u);
}
__device__ __forceinline__ float dec_f32(unsigned u) {
  unsigned v = (u & 0x80000000u) ? (u ^ 0x80000000u) : ~u;
  return __uint_as_float(v);
}

// ---------- kernel 1: per-edge attention logits + segment max ----------
__global__ __launch_bounds__(256) void k_edge_att(
    const float* __restrict__ nodes, const float* __restrict__ rels,
    const int* __restrict__ froms, const int* __restrict__ tos,
    const int* __restrict__ relidx, float* __restrict__ att,
    unsigned* __restrict__ rowmax) {
  int e = blockIdx.x * 8 + (threadIdx.x >> 5);
  int lane = threadIdx.x & 31;
  int f = froms[e], t = tos[e], r = relidx[e];
  const float4 a = ((const float4*)(nodes + (size_t)f * K_DIM))[lane];
  const float4 b = ((const float4*)(nodes + (size_t)t * K_DIM))[lane];
  const float4 c = ((const float4*)(rels + (size_t)r * K_DIM))[lane];
  float s = a.x * b.x * c.x + a.y * b.y * c.y + a.z * b.z * c.z + a.w * b.w * c.w;
#pragma unroll
  for (int o = 16; o; o >>= 1) s += __shfl_xor(s, o);
  if (lane == 0) {
    att[e] = s;
    atomicMax(rowmax + (f + r * N_NODES), enc_f32(s));
  }
}

// ---------- kernel 2: exp(att - rowmax), segment denom ----------
__global__ __launch_bounds__(256) void k_edge_exp(
    const int* __restrict__ froms, const int* __restrict__ relidx,
    const unsigned* __restrict__ rowmax, float* __restrict__ att_ex,
    float* __restrict__ denom) {
  int e = blockIdx.x * 256 + threadIdx.x;
  if (e >= E_EDGES) return;
  int row = froms[e] + relidx[e] * N_NODES;
  float m = dec_f32(rowmax[row]);
  float ex = expf(att_ex[e] - m);
  att_ex[e] = ex;
  atomicAdd(denom + row, ex);
}

// ---------- kernel 3: scatter-agg ----------
// rel_filter < 0: write into nw layout [n][r*128+k] (full path)
// rel_filter = r: only edges of relation r, write into node_agg [n][128]
__global__ __launch_bounds__(256) void k_scatter(
    const float* __restrict__ nodes, const int* __restrict__ froms,
    const int* __restrict__ tos, const int* __restrict__ relidx,
    const float* __restrict__ ex, const float* __restrict__ denom,
    float* __restrict__ agg, int rel_filter) {
  int e = blockIdx.x * 8 + (threadIdx.x >> 5);
  int lane = threadIdx.x & 31;
  int r = relidx[e];
  if (rel_filter >= 0 && r != rel_filter) return;
  int f = froms[e], t = tos[e];
  float val = ex[e] / denom[f + r * N_NODES];
  const float4 b = ((const float4*)(nodes + (size_t)t * K_DIM))[lane];
  float* dst;
  if (rel_filter >= 0)
    dst = agg + (size_t)f * K_DIM + lane * 4;
  else
    dst = agg + (size_t)f * (R_REL * K_DIM) + r * K_DIM + lane * 4;
  atomicAdd(dst + 0, val * b.x);
  atomicAdd(dst + 1, val * b.y);
  atomicAdd(dst + 2, val * b.z);
  atomicAdd(dst + 3, val * b.w);
}

// ---------- tiled fp32 GEMM: C[M,NB] (+)= A[M,KA] @ B[KA,NB] ----------
// BM=64, BN=64, BK=32, 256 threads, 4x4 microtile.
// EPI: 0 = C = acc + bias; 1 = C = relu(acc + bias);
//      2 = C += acc;       3 = C = relu(C + acc)
template <int KA, int NB, int EPI>
__global__ __launch_bounds__(256) void k_gemm(
    const float* __restrict__ A, const float* __restrict__ B,
    const float* __restrict__ bias, float* __restrict__ C) {
  __shared__ float As[32][68];
  __shared__ float Bs[32][68];

  int tid = threadIdx.x;
  int tx = tid & 15, ty = tid >> 4;
  int m0 = blockIdx.x * 64, n0 = blockIdx.y * 64;

  float acc[4][4] = {};

  for (int kt = 0; kt < KA; kt += 32) {
    {  // A tile (64 m x 32 k) -> As[kk][m]
      int ar = tid >> 3;  // 0..31
      int aj = tid & 7;   // k/4
#pragma unroll
      for (int i = 0; i < 2; ++i) {
        int m = ar + i * 32;
        int gm = m0 + m;
        float4 v = make_float4(0.f, 0.f, 0.f, 0.f);
        if (gm < N_NODES) v = *(const float4*)(A + (size_t)gm * KA + kt + aj * 4);
        As[aj * 4 + 0][m] = v.x;
        As[aj * 4 + 1][m] = v.y;
        As[aj * 4 + 2][m] = v.z;
        As[aj * 4 + 3][m] = v.w;
      }
    }
    {  // B tile (32 k x 64 n)
      int br = tid >> 4;
      int bj = tid & 15;
#pragma unroll
      for (int i = 0; i < 2; ++i) {
        int rr = br + i * 16;
        float4 v = *(const float4*)(B + (size_t)(kt + rr) * NB + n0 + bj * 4);
        *(float4*)&Bs[rr][bj * 4] = v;
      }
    }
    __syncthreads();

#pragma unroll
    for (int kk = 0; kk < 32; ++kk) {
      float4 av = *(const float4*)&As[kk][ty * 4];
      float4 bv = *(const float4*)&Bs[kk][tx * 4];
      float a[4] = {av.x, av.y, av.z, av.w};
      float b[4] = {bv.x, bv.y, bv.z, bv.w};
#pragma unroll
      for (int i = 0; i < 4; ++i)
#pragma unroll
        for (int j = 0; j < 4; ++j) acc[i][j] += a[i] * b[j];
    }
    __syncthreads();
  }

  float bv[4] = {0.f, 0.f, 0.f, 0.f};
  if (EPI == 0 || EPI == 1) {
#pragma unroll
    for (int j = 0; j < 4; ++j) bv[j] = bias[n0 + tx * 4 + j];
  }
#pragma unroll
  for (int i = 0; i < 4; ++i) {
    int gm = m0 + ty * 4 + i;
    if (gm >= N_NODES) continue;
#pragma unroll
    for (int j = 0; j < 4; ++j) {
      size_t idx = (size_t)gm * NB + n0 + tx * 4 + j;
      float v = acc[i][j];
      if (EPI == 0 || EPI == 1) v += bv[j];
      if (EPI == 2 || EPI == 3) v += C[idx];
      if (EPI == 1 || EPI == 3) v = fmaxf(v, 0.f);
      C[idx] = v;
    }
  }
}

// ---------- batch-norm column stats (sum, sumsq in double) ----------
__global__ __launch_bounds__(256) void k_bnstats(const float* __restrict__ h,
                                                 double* __restrict__ stats) {
  int c = threadIdx.x & 127;
  int half = threadIdx.x >> 7;
  double s = 0.0, sq = 0.0;
  for (int row = blockIdx.x * 2 + half; row < N_NODES; row += gridDim.x * 2) {
    float v = h[(size_t)row * K_DIM + c];
    s += v;
    sq += (double)v * v;
  }
  __shared__ double sh[256];
  sh[threadIdx.x] = s;
  __syncthreads();
  if (half == 0) atomicAdd(&stats[c], s + sh[threadIdx.x + 128]);
  __syncthreads();
  sh[threadIdx.x] = sq;
  __syncthreads();
  if (half == 0) atomicAdd(&stats[128 + c], sq + sh[threadIdx.x + 128]);
}

__global__ void k_bnfin(const double* __restrict__ stats,
                        const float* __restrict__ normparams,
                        float* __restrict__ fstats) {
  int c = threadIdx.x;  // 128 threads
  double s = stats[c], sq = stats[128 + c];
  double mean = s / N_NODES;
  double var = (sq - mean * mean * N_NODES) / (N_NODES - 1);
  float gamma = normparams[0];
  fstats[c] = (float)mean;
  fstats[128 + c] = (float)((double)gamma / sqrt(var + EPS));
}

__global__ __launch_bounds__(256) void k_bnapply(
    float* __restrict__ h, const float* __restrict__ fstats,
    const float* __restrict__ normparams) {
  int idx = blockIdx.x * 256 + threadIdx.x;  // float4 index
  if (idx >= N_NODES * 32) return;
  float beta = normparams[1];
  float4 v = ((float4*)h)[idx];
  int c4 = (idx & 31) * 4;
  v.x = (v.x - fstats[c4 + 0]) * fstats[128 + c4 + 0] + beta;
  v.y = (v.y - fstats[c4 + 1]) * fstats[128 + c4 + 1] + beta;
  v.z = (v.z - fstats[c4 + 2]) * fstats[128 + c4 + 2] + beta;
  v.w = (v.w - fstats[c4 + 3]) * fstats[128 + c4 + 3] + beta;
  ((float4*)h)[idx] = v;
}

extern "C" void kernel_launch(void* const* d_in, const int* in_sizes, int n_in,
                              void* d_out, int out_size, void* d_ws, size_t ws_size,
                              hipStream_t stream) {
  (void)in_sizes; (void)n_in; (void)out_size;
  const float* nodes = (const float*)d_in[0];
  const float* rels = (const float*)d_in[1];
  const float* W1 = (const float*)d_in[2];
  const float* b1 = (const float*)d_in[3];
  const float* W2 = (const float*)d_in[4];
  const float* b2 = (const float*)d_in[5];
  const float* normparams = (const float*)d_in[6];
  const int* froms = (const int*)d_in[7];
  const int* tos = (const int*)d_in[8];
  const int* relidx = (const int*)d_in[9];
  float* out = (float*)d_out;
  char* ws = (char*)d_ws;

  const size_t NEED_A = 312403072ull;  // nw(204.8M)+denom+rowmax+stats+h1(102.4M)+att+fstats

  if (ws_size >= NEED_A) {
    // ---- Path A: full nw materialization, single big GEMM1 ----
    float* nw = (float*)(ws);                        // 204,800,000
    float* denom = (float*)(ws + 204800000);         //   1,600,000
    unsigned* rowmax = (unsigned*)(ws + 206400000);  //   1,600,000
    double* stats = (double*)(ws + 208000000);       //       2,048
    float* h1 = (float*)(ws + 208002048);            // 102,400,000
    float* att = (float*)(ws + 310402048);           //   2,000,000
    float* fstats = (float*)(ws + 312402048);        //       1,024

    hipMemsetAsync(ws, 0, 208002048, stream);  // nw, denom, rowmax, stats

    k_edge_att<<<E_EDGES / 8, 256, 0, stream>>>(nodes, rels, froms, tos,
                                                relidx, att, rowmax);
    k_edge_exp<<<(E_EDGES + 255) / 256, 256, 0, stream>>>(froms, relidx,
                                                          rowmax, att, denom);
    k_scatter<<<E_EDGES / 8, 256, 0, stream>>>(nodes, froms, tos, relidx, att,
                                               denom, nw, -1);
    // h1 = relu(nw @ W1 + b1)
    k_gemm<1024, 512, 1><<<dim3(782, 8), 256, 0, stream>>>(nw, W1, b1, h1);
    // out = h1 @ W2 + b2
    k_gemm<512, 128, 0><<<dim3(782, 2), 256, 0, stream>>>(h1, W2, b2, out);

    k_bnstats<<<256, 256, 0, stream>>>(out, stats);
    k_bnfin<<<1, 128, 0, stream>>>(stats, normparams, fstats);
    k_bnapply<<<(N_NODES * 32 + 255) / 256, 256, 0, stream>>>(out, fstats,
                                                              normparams);
  } else {
    // ---- Path B: per-relation staging (rel_index is sorted), ~133 MB ----
    float* nagg = (float*)(ws);                      //  25,600,000
    float* h1 = (float*)(ws + 25600000);             // 102,400,000
    float* denom = (float*)(ws + 128000000);         //   1,600,000
    unsigned* rowmax = (unsigned*)(ws + 129600000);  //   1,600,000
    double* stats = (double*)(ws + 131200000);       //       2,048
    float* att = (float*)(ws + 131202048);           //   2,000,000
    float* fstats = (float*)(ws + 133202048);        //       1,024

    hipMemsetAsync(ws + 128000000, 0, 3202048, stream);  // denom,rowmax,stats

    k_edge_att<<<E_EDGES / 8, 256, 0, stream>>>(nodes, rels, froms, tos,
                                                relidx, att, rowmax);
    k_edge_exp<<<(E_EDGES + 255) / 256, 256, 0, stream>>>(froms, relidx,
                                                          rowmax, att, denom);
    for (int r = 0; r < R_REL; ++r) {
      hipMemsetAsync(nagg, 0, 25600000, stream);
      k_scatter<<<E_EDGES / 8, 256, 0, stream>>>(nodes, froms, tos, relidx,
                                                 att, denom, nagg, r);
      const float* Br = W1 + (size_t)r * K_DIM * 512;
      if (r == 0)
        k_gemm<128, 512, 0><<<dim3(782, 8), 256, 0, stream>>>(nagg, Br, b1, h1);
      else if (r == R_REL - 1)
        k_gemm<128, 512, 3><<<dim3(782, 8), 256, 0, stream>>>(nagg, Br, b1, h1);
      else
        k_gemm<128, 512, 2><<<dim3(782, 8), 256, 0, stream>>>(nagg, Br, b1, h1);
    }
    k_gemm<512, 128, 0><<<dim3(782, 2), 256, 0, stream>>>(h1, W2, b2, out);

    k_bnstats<<<256, 256, 0, stream>>>(out, stats);
    k_bnfin<<<1, 128, 0, stream>>>(stats, normparams, fstats);
    k_bnapply<<<(N_NODES * 32 + 255) / 256, 256, 0, stream>>>(out, fstats,
                                                              normparams);
  }
}

// Round 3
// 1528.845 us; speedup vs baseline: 1.3851x; 1.3851x over previous
//
#include <hip/hip_runtime.h>
#include <math.h>

#define N_NODES 50000
#define K_DIM 128
#define R_REL 8
#define E_EDGES 500000
#define EPS 1e-8

typedef short bf16x8 __attribute__((ext_vector_type(8)));
typedef float f32x4 __attribute__((ext_vector_type(4)));

// ---------- bf16 helpers (RNE) ----------
__device__ __forceinline__ unsigned short f2bf(float x) {
  unsigned u = __float_as_uint(x);
  u = u + 0x7FFFu + ((u >> 16) & 1u);
  return (unsigned short)(u >> 16);
}
__device__ __forceinline__ float bf2f(unsigned short h) {
  return __uint_as_float(((unsigned)h) << 16);
}

// ---------- order-preserving float<->uint encoding for atomicMax ----------
__device__ __forceinline__ unsigned enc_f32(float f) {
  unsigned u = __float_as_uint(f);
  return (u & 0x80000000u) ? ~u : (u | 0x80000000u);
}
__device__ __forceinline__ float dec_f32(unsigned u) {
  unsigned v = (u & 0x80000000u) ? (u ^ 0x80000000u) : ~u;
  return __uint_as_float(v);
}

// ---------- kernel 1: per-edge attention logits + segment max ----------
__global__ __launch_bounds__(256) void k_edge_att(
    const float* __restrict__ nodes, const float* __restrict__ rels,
    const int* __restrict__ froms, const int* __restrict__ tos,
    const int* __restrict__ relidx, float* __restrict__ att,
    unsigned* __restrict__ rowmax) {
  int e = blockIdx.x * 8 + (threadIdx.x >> 5);
  int lane = threadIdx.x & 31;
  int f = froms[e], t = tos[e], r = relidx[e];
  const float4 a = ((const float4*)(nodes + (size_t)f * K_DIM))[lane];
  const float4 b = ((const float4*)(nodes + (size_t)t * K_DIM))[lane];
  const float4 c = ((const float4*)(rels + (size_t)r * K_DIM))[lane];
  float s = a.x * b.x * c.x + a.y * b.y * c.y + a.z * b.z * c.z + a.w * b.w * c.w;
#pragma unroll
  for (int o = 16; o; o >>= 1) s += __shfl_xor(s, o);
  if (lane == 0) {
    att[e] = s;
    atomicMax(rowmax + (f + r * N_NODES), enc_f32(s));
  }
}

// ---------- kernel 2: exp(att - rowmax), segment denom ----------
__global__ __launch_bounds__(256) void k_edge_exp(
    const int* __restrict__ froms, const int* __restrict__ relidx,
    const unsigned* __restrict__ rowmax, float* __restrict__ att_ex,
    float* __restrict__ denom) {
  int e = blockIdx.x * 256 + threadIdx.x;
  if (e >= E_EDGES) return;
  int row = froms[e] + relidx[e] * N_NODES;
  float m = dec_f32(rowmax[row]);
  float ex = expf(att_ex[e] - m);
  att_ex[e] = ex;
  atomicAdd(denom + row, ex);
}

// ---------- relation range boundaries (rel_index is sorted) ----------
__global__ void k_ranges(const int* __restrict__ relidx, int* __restrict__ ranges) {
  int r = threadIdx.x;
  if (r > R_REL) return;
  int lo = 0, hi = E_EDGES;
  while (lo < hi) {
    int mid = (lo + hi) >> 1;
    if (relidx[mid] < r) lo = mid + 1; else hi = mid;
  }
  ranges[r] = lo;
}

// ---------- range-based scatter into nagg [n][(r-rb0)*128+k] ----------
__global__ __launch_bounds__(256) void k_scatter_r(
    const float* __restrict__ nodes, const int* __restrict__ froms,
    const int* __restrict__ tos, const int* __restrict__ relidx,
    const float* __restrict__ ex, const float* __restrict__ denom,
    const int* __restrict__ ranges, int rb0, int RB, float* __restrict__ nagg) {
  int lo = ranges[rb0], hi = ranges[rb0 + RB];
  int lane = threadIdx.x & 31, grp = threadIdx.x >> 5;
  int stride = RB * K_DIM;
  for (int e = lo + blockIdx.x * 8 + grp; e < hi; e += gridDim.x * 8) {
    int f = froms[e], t = tos[e], r = relidx[e];
    float val = ex[e] / denom[f + r * N_NODES];
    const float4 b = ((const float4*)(nodes + (size_t)t * K_DIM))[lane];
    float* dst = nagg + (size_t)f * stride + (r - rb0) * K_DIM + lane * 4;
    atomicAdd(dst + 0, val * b.x);
    atomicAdd(dst + 1, val * b.y);
    atomicAdd(dst + 2, val * b.z);
    atomicAdd(dst + 3, val * b.w);
  }
}

// ---------- weight prep: W [K][Nw] f32 -> swizzled split-bf16 tile image ----------
// img layout: [ktile(K/32)][ntile(Nw/128)][plane hi/lo][8192 B tile]
// tile inner: byte = (row*64 + kin*2) ^ ((row&7)<<4), row = n&127
__global__ __launch_bounds__(256) void k_prep_w(
    const float* __restrict__ W, unsigned short* __restrict__ img,
    int Nw, int NT, int S) {
  int g = blockIdx.x * 256 + threadIdx.x;
  int n = g >> S;
  int k8 = g & ((1 << S) - 1);
  int k = k8 * 8;
  if (n >= Nw) return;
  int ktile = k >> 5, kin = k & 31;
  int row = n & 127, ntl = n >> 7;
  char* dst0 = (char*)img + ((size_t)(ktile * NT + ntl) * 2) * 8192;
  char* dst1 = dst0 + 8192;
  int swz = (row & 7) << 4;
  unsigned short hi[8], lo[8];
#pragma unroll
  for (int j = 0; j < 8; ++j) {
    float x = W[(size_t)(k + j) * Nw + n];
    hi[j] = f2bf(x);
    lo[j] = f2bf(x - bf2f(hi[j]));
  }
#pragma unroll
  for (int j = 0; j < 8; j += 2) {
    int byo = (row * 64 + (kin + j) * 2) ^ swz;
    *(unsigned*)(dst0 + byo) = (unsigned)hi[j] | ((unsigned)hi[j + 1] << 16);
    *(unsigned*)(dst1 + byo) = (unsigned)lo[j] | ((unsigned)lo[j + 1] << 16);
  }
}

// ---------- split-bf16 MFMA GEMM: C[M,NB] (+)= A[M,KA] @ B + bias ----------
// A fp32 (split on the fly); B from pre-swizzled split image.
// 128x128 block tile, 4 waves (2x2), 64x64 per wave, 16x16x32 MFMA, 3 passes.
// EPI: 0 = C = acc + bias; 1 = C += acc; 2 = C = relu(C + acc)
template <int KA, int NB, int EPI>
__global__ __launch_bounds__(256) void k_gemm_mfma(
    const float* __restrict__ A, const unsigned short* __restrict__ Bimg,
    const float* __restrict__ bias, float* __restrict__ C) {
  constexpr int NT = NB / 128;
  constexpr int NSTEP = KA / 32;
  __shared__ uint4 ldsbuf[2048];  // 32 KB: Ah 8K | Al 8K | Bh 8K | Bl 8K
  char* lds = (char*)ldsbuf;
  char* Ah = lds;
  char* Al = lds + 8192;
  char* Bp = lds + 16384;

  int tid = threadIdx.x;
  // bijective XCD-chunk swizzle (m204): consecutive logical blocks share an XCD
  int nwg = gridDim.x;
  int q = nwg >> 3, r = nwg & 7;
  int xcd = blockIdx.x & 7, bidx = blockIdx.x >> 3;
  int wg = (xcd < r ? xcd * (q + 1) : r * (q + 1) + (xcd - r) * q) + bidx;
  int nt = wg % NT;
  int mt = wg / NT;
  int m0 = mt * 128, n0 = nt * 128;

  int l = tid & 63, w = tid >> 6;
  int wm = (w >> 1) * 64, wn = (w & 1) * 64;
  int lrow = l & 15, lk16 = (l >> 4) * 16;  // k-slice byte offset within 64B row

  f32x4 acc[4][4];
#pragma unroll
  for (int i = 0; i < 4; ++i)
#pragma unroll
    for (int j = 0; j < 4; ++j)
#pragma unroll
      for (int cc = 0; cc < 4; ++cc) acc[i][j][cc] = 0.f;

  int srow = tid >> 1;   // staging row 0..127
  int shalf = tid & 1;   // k half (16 elems)

  for (int kt = 0; kt < NSTEP; ++kt) {
    __syncthreads();
    {  // A stage: reg-load f32, split hi/lo, swizzled ds_write
      int gm = m0 + srow;
      const float* src = A + (size_t)gm * KA + kt * 32 + shalf * 16;
      int swz = (srow & 7) << 4;
      int b0 = srow * 64 + shalf * 32;
#pragma unroll
      for (int qd = 0; qd < 4; ++qd) {
        float4 v = make_float4(0.f, 0.f, 0.f, 0.f);
        if (gm < N_NODES) v = *(const float4*)(src + qd * 4);
        unsigned short h0 = f2bf(v.x), h1 = f2bf(v.y), h2 = f2bf(v.z), h3 = f2bf(v.w);
        unsigned short g0 = f2bf(v.x - bf2f(h0)), g1 = f2bf(v.y - bf2f(h1));
        unsigned short g2 = f2bf(v.z - bf2f(h2)), g3 = f2bf(v.w - bf2f(h3));
        int byo = (b0 + qd * 8) ^ swz;
        *(uint2*)(Ah + byo) = make_uint2((unsigned)h0 | ((unsigned)h1 << 16),
                                         (unsigned)h2 | ((unsigned)h3 << 16));
        *(uint2*)(Al + byo) = make_uint2((unsigned)g0 | ((unsigned)g1 << 16),
                                         (unsigned)g2 | ((unsigned)g3 << 16));
      }
    }
    {  // B copy: 16 KB pre-swizzled slab (hi plane then lo plane)
      const char* bsrc = (const char*)Bimg + ((size_t)(kt * NT + nt)) * 16384;
#pragma unroll
      for (int qd = 0; qd < 4; ++qd) {
        int c = tid + qd * 256;
        *(uint4*)(Bp + c * 16) = *(const uint4*)(bsrc + c * 16);
      }
    }
    __syncthreads();

    bf16x8 ahf[4], alf[4], bhf[4], blf[4];
#pragma unroll
    for (int i = 0; i < 4; ++i) {
      int row = wm + i * 16 + lrow;
      int byo = (row * 64 + lk16) ^ ((row & 7) << 4);
      ahf[i] = *(bf16x8*)(Ah + byo);
      alf[i] = *(bf16x8*)(Al + byo);
    }
#pragma unroll
    for (int j = 0; j < 4; ++j) {
      int row = wn + j * 16 + lrow;
      int byo = (row * 64 + lk16) ^ ((row & 7) << 4);
      bhf[j] = *(bf16x8*)(Bp + byo);
      blf[j] = *(bf16x8*)(Bp + 8192 + byo);
    }
#pragma unroll
    for (int i = 0; i < 4; ++i)
#pragma unroll
      for (int j = 0; j < 4; ++j) {
        acc[i][j] = __builtin_amdgcn_mfma_f32_16x16x32_bf16(ahf[i], bhf[j], acc[i][j], 0, 0, 0);
        acc[i][j] = __builtin_amdgcn_mfma_f32_16x16x32_bf16(ahf[i], blf[j], acc[i][j], 0, 0, 0);
        acc[i][j] = __builtin_amdgcn_mfma_f32_16x16x32_bf16(alf[i], bhf[j], acc[i][j], 0, 0, 0);
      }
  }

  // epilogue: C row = (l>>4)*4 + reg, col = l&15 within each 16x16 frag
#pragma unroll
  for (int j = 0; j < 4; ++j) {
    int colg = n0 + wn + j * 16 + lrow;
    float bj = (EPI == 0) ? bias[colg] : 0.f;
#pragma unroll
    for (int i = 0; i < 4; ++i) {
      int rbase = m0 + wm + i * 16 + (l >> 4) * 4;
#pragma unroll
      for (int reg = 0; reg < 4; ++reg) {
        int gm = rbase + reg;
        if (gm >= N_NODES) continue;
        size_t idx2 = (size_t)gm * NB + colg;
        float v = acc[i][j][reg];
        if (EPI == 0) v += bj;
        else v += C[idx2];
        if (EPI == 2) v = fmaxf(v, 0.f);
        C[idx2] = v;
      }
    }
  }
}

// ---------- batch-norm ----------
__global__ __launch_bounds__(256) void k_bnstats(const float* __restrict__ h,
                                                 double* __restrict__ stats) {
  int c = threadIdx.x & 127;
  int half = threadIdx.x >> 7;
  double s = 0.0, sq = 0.0;
  for (int row = blockIdx.x * 2 + half; row < N_NODES; row += gridDim.x * 2) {
    float v = h[(size_t)row * K_DIM + c];
    s += v;
    sq += (double)v * v;
  }
  __shared__ double sh[256];
  sh[threadIdx.x] = s;
  __syncthreads();
  if (half == 0) atomicAdd(&stats[c], s + sh[threadIdx.x + 128]);
  __syncthreads();
  sh[threadIdx.x] = sq;
  __syncthreads();
  if (half == 0) atomicAdd(&stats[128 + c], sq + sh[threadIdx.x + 128]);
}

__global__ void k_bnfin(const double* __restrict__ stats,
                        const float* __restrict__ normparams,
                        float* __restrict__ fstats) {
  int c = threadIdx.x;
  double s = stats[c], sq = stats[128 + c];
  double mean = s / N_NODES;
  double var = (sq - mean * mean * N_NODES) / (N_NODES - 1);
  float gamma = normparams[0];
  fstats[c] = (float)mean;
  fstats[128 + c] = (float)((double)gamma / sqrt(var + EPS));
}

__global__ __launch_bounds__(256) void k_bnapply(
    float* __restrict__ h, const float* __restrict__ fstats,
    const float* __restrict__ normparams) {
  int idx = blockIdx.x * 256 + threadIdx.x;
  if (idx >= N_NODES * 32) return;
  float beta = normparams[1];
  float4 v = ((float4*)h)[idx];
  int c4 = (idx & 31) * 4;
  v.x = (v.x - fstats[c4 + 0]) * fstats[128 + c4 + 0] + beta;
  v.y = (v.y - fstats[c4 + 1]) * fstats[128 + c4 + 1] + beta;
  v.z = (v.z - fstats[c4 + 2]) * fstats[128 + c4 + 2] + beta;
  v.w = (v.w - fstats[c4 + 3]) * fstats[128 + c4 + 3] + beta;
  ((float4*)h)[idx] = v;
}

extern "C" void kernel_launch(void* const* d_in, const int* in_sizes, int n_in,
                              void* d_out, int out_size, void* d_ws, size_t ws_size,
                              hipStream_t stream) {
  (void)in_sizes; (void)n_in; (void)out_size;
  const float* nodes = (const float*)d_in[0];
  const float* rels = (const float*)d_in[1];
  const float* W1 = (const float*)d_in[2];
  const float* b1 = (const float*)d_in[3];
  const float* W2 = (const float*)d_in[4];
  const float* b2 = (const float*)d_in[5];
  const float* normparams = (const float*)d_in[6];
  const int* froms = (const int*)d_in[7];
  const int* tos = (const int*)d_in[8];
  const int* relidx = (const int*)d_in[9];
  float* out = (float*)d_out;
  char* ws = (char*)d_ws;

  // relation batch size by workspace tier (B1 footprint == proven 133,203,072 B)
  int RB = (ws_size >= 210003072ull) ? 4 : (ws_size >= 158803072ull) ? 2 : 1;
  size_t SZ_NAGG = (size_t)RB * 25600000ull;

  float* nagg = (float*)ws;
  float* h1 = (float*)(ws + SZ_NAGG);
  char* fix = ws + SZ_NAGG + 102400000;
  float* denom = (float*)fix;                       // 1,600,000
  unsigned* rowmax = (unsigned*)(fix + 1600000);    // 1,600,000 (reused post-exp)
  double* stats = (double*)(fix + 3200000);         //     2,048
  float* att = (float*)(fix + 3202048);             // 2,000,000
  float* fstats = (float*)(fix + 5202048);          //     1,024
  unsigned short* W2s = (unsigned short*)rowmax;              // 262,144 (post-exp)
  int* ranges = (int*)((char*)rowmax + 262144);               //      64 (post-exp)
  unsigned short* W1s = (unsigned short*)d_out;               // 2,097,152 (pre-GEMM2)

  hipMemsetAsync(denom, 0, 3202048, stream);  // denom, rowmax, stats

  k_edge_att<<<E_EDGES / 8, 256, 0, stream>>>(nodes, rels, froms, tos, relidx,
                                              att, rowmax);
  k_edge_exp<<<(E_EDGES + 255) / 256, 256, 0, stream>>>(froms, relidx, rowmax,
                                                        att, denom);
  // rowmax dead from here; its space holds W2s + ranges
  k_ranges<<<1, 16, 0, stream>>>(relidx, ranges);
  k_prep_w<<<256, 256, 0, stream>>>(W1, W1s, 512, 4, 7);  // K=1024,N=512 -> S=7
  k_prep_w<<<32, 256, 0, stream>>>(W2, W2s, 128, 1, 6);   // K=512, N=128 -> S=6

  const int rounds = 8 / RB;
  for (int b = 0; b < rounds; ++b) {
    hipMemsetAsync(nagg, 0, SZ_NAGG, stream);
    k_scatter_r<<<1024, 256, 0, stream>>>(nodes, froms, tos, relidx, att,
                                          denom, ranges, b * RB, RB, nagg);
    const unsigned short* Bimg = W1s + (size_t)(b * RB * 4) * 4 * 2 * 4096;
    if (RB == 4) {
      if (b == 0)
        k_gemm_mfma<512, 512, 0><<<1564, 256, 0, stream>>>(nagg, Bimg, b1, h1);
      else
        k_gemm_mfma<512, 512, 2><<<1564, 256, 0, stream>>>(nagg, Bimg, b1, h1);
    } else if (RB == 2) {
      if (b == 0)
        k_gemm_mfma<256, 512, 0><<<1564, 256, 0, stream>>>(nagg, Bimg, b1, h1);
      else if (b < rounds - 1)
        k_gemm_mfma<256, 512, 1><<<1564, 256, 0, stream>>>(nagg, Bimg, b1, h1);
      else
        k_gemm_mfma<256, 512, 2><<<1564, 256, 0, stream>>>(nagg, Bimg, b1, h1);
    } else {
      if (b == 0)
        k_gemm_mfma<128, 512, 0><<<1564, 256, 0, stream>>>(nagg, Bimg, b1, h1);
      else if (b < rounds - 1)
        k_gemm_mfma<128, 512, 1><<<1564, 256, 0, stream>>>(nagg, Bimg, b1, h1);
      else
        k_gemm_mfma<128, 512, 2><<<1564, 256, 0, stream>>>(nagg, Bimg, b1, h1);
    }
  }

  // GEMM2: out = h1 @ W2 + b2
  k_gemm_mfma<512, 128, 0><<<391, 256, 0, stream>>>(h1, W2s, b2, out);

  k_bnstats<<<256, 256, 0, stream>>>(out, stats);
  k_bnfin<<<1, 128, 0, stream>>>(stats, normparams, fstats);
  k_bnapply<<<(N_NODES * 32 + 255) / 256, 256, 0, stream>>>(out, fstats,
                                                            normparams);
}

// Round 6
// 793.777 us; speedup vs baseline: 2.6677x; 1.9260x over previous
//
#include <hip/hip_runtime.h>
#include <math.h>

#define N_NODES 50000
#define K_DIM 128
#define R_REL 8
#define E_EDGES 500000
#define NROWS 400000      // N_NODES * R_REL
#define SCAN_BLOCKS 1563  // ceil(NROWS/256)
#define EPS 1e-8

typedef short bf16x8 __attribute__((ext_vector_type(8)));
typedef float f32x4 __attribute__((ext_vector_type(4)));

// ---------- bf16 helpers (RNE) ----------
__device__ __forceinline__ unsigned short f2bf(float x) {
  unsigned u = __float_as_uint(x);
  u = u + 0x7FFFu + ((u >> 16) & 1u);
  return (unsigned short)(u >> 16);
}
__device__ __forceinline__ float bf2f(unsigned short h) {
  return __uint_as_float(((unsigned)h) << 16);
}

// ---------- order-preserving float<->uint encoding for atomicMax ----------
__device__ __forceinline__ unsigned enc_f32(float f) {
  unsigned u = __float_as_uint(f);
  return (u & 0x80000000u) ? ~u : (u | 0x80000000u);
}
__device__ __forceinline__ float dec_f32(unsigned u) {
  unsigned v = (u & 0x80000000u) ? (u ^ 0x80000000u) : ~u;
  return __uint_as_float(v);
}

// ---------- kernel 1: per-edge attention logits + segment max ----------
__global__ __launch_bounds__(256) void k_edge_att(
    const float* __restrict__ nodes, const float* __restrict__ rels,
    const int* __restrict__ froms, const int* __restrict__ tos,
    const int* __restrict__ relidx, float* __restrict__ att,
    unsigned* __restrict__ rowmax) {
  int e = blockIdx.x * 8 + (threadIdx.x >> 5);
  int lane = threadIdx.x & 31;
  int f = froms[e], t = tos[e], r = relidx[e];
  const float4 a = ((const float4*)(nodes + (size_t)f * K_DIM))[lane];
  const float4 b = ((const float4*)(nodes + (size_t)t * K_DIM))[lane];
  const float4 c = ((const float4*)(rels + (size_t)r * K_DIM))[lane];
  float s = a.x * b.x * c.x + a.y * b.y * c.y + a.z * b.z * c.z + a.w * b.w * c.w;
#pragma unroll
  for (int o = 16; o; o >>= 1) s += __shfl_xor(s, o);
  if (lane == 0) {
    att[e] = s;
    atomicMax(rowmax + (f + r * N_NODES), enc_f32(s));
  }
}

// ---------- kernel 2: exp(att - rowmax) + segment denom + row counts ----------
__global__ __launch_bounds__(256) void k_edge_exp_cnt(
    const int* __restrict__ froms, const int* __restrict__ relidx,
    const unsigned* __restrict__ rowmax, float* __restrict__ att_ex,
    float* __restrict__ denom, int* __restrict__ count) {
  int e = blockIdx.x * 256 + threadIdx.x;
  if (e >= E_EDGES) return;
  int row = froms[e] + relidx[e] * N_NODES;
  float m = dec_f32(rowmax[row]);
  float ex = expf(att_ex[e] - m);
  att_ex[e] = ex;
  atomicAdd(denom + row, ex);
  atomicAdd(count + row, 1);
}

// ---------- kernel 3: vals[e] = ex[e] / denom[row]  (in place) ----------
__global__ __launch_bounds__(256) void k_vals(
    const int* __restrict__ froms, const int* __restrict__ relidx,
    const float* __restrict__ denom, float* __restrict__ vals) {
  int e = blockIdx.x * 256 + threadIdx.x;
  if (e >= E_EDGES) return;
  int row = froms[e] + relidx[e] * N_NODES;
  vals[e] /= denom[row];
}

// ---------- CSR build: scan (3 kernels) + fill ----------
__global__ __launch_bounds__(256) void k_scan1(const int* __restrict__ count,
                                               int* __restrict__ aux) {
  __shared__ int sh[256];
  int i = blockIdx.x * 256 + threadIdx.x;
  sh[threadIdx.x] = (i < NROWS) ? count[i] : 0;
  __syncthreads();
  for (int s = 128; s; s >>= 1) {
    if (threadIdx.x < s) sh[threadIdx.x] += sh[threadIdx.x + s];
    __syncthreads();
  }
  if (threadIdx.x == 0) aux[blockIdx.x] = sh[0];
}

__global__ void k_scan2(int* __restrict__ aux) {  // single block
  __shared__ int sh[256];
  __shared__ int running;
  if (threadIdx.x == 0) running = 0;
  __syncthreads();
  for (int base = 0; base < SCAN_BLOCKS; base += 256) {
    int i = base + threadIdx.x;
    int v = (i < SCAN_BLOCKS) ? aux[i] : 0;
    sh[threadIdx.x] = v;
    __syncthreads();
    for (int off = 1; off < 256; off <<= 1) {
      int t = (threadIdx.x >= off) ? sh[threadIdx.x - off] : 0;
      __syncthreads();
      sh[threadIdx.x] += t;
      __syncthreads();
    }
    int incl = sh[threadIdx.x];
    if (i < SCAN_BLOCKS) aux[i] = incl - v + running;
    __syncthreads();
    if (threadIdx.x == 0) running += sh[255];
    __syncthreads();
  }
}

__global__ __launch_bounds__(256) void k_scan3(const int* __restrict__ count,
                                               const int* __restrict__ aux,
                                               int* __restrict__ row_ptr,
                                               int* __restrict__ cursor) {
  __shared__ int sh[256];
  int i = blockIdx.x * 256 + threadIdx.x;
  int v = (i < NROWS) ? count[i] : 0;
  sh[threadIdx.x] = v;
  __syncthreads();
  for (int off = 1; off < 256; off <<= 1) {
    int t = (threadIdx.x >= off) ? sh[threadIdx.x - off] : 0;
    __syncthreads();
    sh[threadIdx.x] += t;
    __syncthreads();
  }
  int excl = sh[threadIdx.x] - v + aux[blockIdx.x];
  if (i < NROWS) {
    row_ptr[i] = excl;
    cursor[i] = excl;
    if (i == NROWS - 1) row_ptr[NROWS] = excl + v;
  }
}

__global__ __launch_bounds__(256) void k_fill(
    const int* __restrict__ froms, const int* __restrict__ relidx,
    int* __restrict__ cursor, int* __restrict__ edge_order) {
  int e = blockIdx.x * 256 + threadIdx.x;
  if (e >= E_EDGES) return;
  int row = froms[e] + relidx[e] * N_NODES;
  int pos = atomicAdd(cursor + row, 1);
  edge_order[pos] = e;
}

// ---------- gather: one 32-lane group per output row, plain stores ----------
__global__ __launch_bounds__(256) void k_gather(
    const float* __restrict__ nodes, const int* __restrict__ tos,
    const float* __restrict__ vals, const int* __restrict__ row_ptr,
    const int* __restrict__ edge_order, int rowbase, float* __restrict__ nw) {
  int g = blockIdx.x * 8 + (threadIdx.x >> 5);  // 0..199999
  int lane = threadIdx.x & 31;
  int row = rowbase + g;
  int rp0 = row_ptr[row], rp1 = row_ptr[row + 1];
  float4 acc = make_float4(0.f, 0.f, 0.f, 0.f);
  for (int p = rp0; p < rp1; ++p) {
    int e = edge_order[p];
    float v = vals[e];
    int t = tos[e];
    const float4 nb = ((const float4*)(nodes + (size_t)t * K_DIM))[lane];
    acc.x += v * nb.x;
    acc.y += v * nb.y;
    acc.z += v * nb.z;
    acc.w += v * nb.w;
  }
  int rl = g / N_NODES;  // relation within batch (0..3)
  int f = g - rl * N_NODES;
  *(float4*)(nw + (size_t)f * 512 + rl * K_DIM + lane * 4) = acc;
}

// ---------- weight prep: W [K][Nw] f32 -> swizzled split-bf16 tile image ----------
__global__ __launch_bounds__(256) void k_prep_w(
    const float* __restrict__ W, unsigned short* __restrict__ img,
    int Nw, int NT, int S) {
  int g = blockIdx.x * 256 + threadIdx.x;
  int n = g >> S;
  int k8 = g & ((1 << S) - 1);
  int k = k8 * 8;
  if (n >= Nw) return;
  int ktile = k >> 5, kin = k & 31;
  int row = n & 127, ntl = n >> 7;
  char* dst0 = (char*)img + ((size_t)(ktile * NT + ntl) * 2) * 8192;
  char* dst1 = dst0 + 8192;
  int swz = (row & 7) << 4;
  unsigned short hi[8], lo[8];
#pragma unroll
  for (int j = 0; j < 8; ++j) {
    float x = W[(size_t)(k + j) * Nw + n];
    hi[j] = f2bf(x);
    lo[j] = f2bf(x - bf2f(hi[j]));
  }
#pragma unroll
  for (int j = 0; j < 8; j += 2) {
    int byo = (row * 64 + (kin + j) * 2) ^ swz;
    *(unsigned*)(dst0 + byo) = (unsigned)hi[j] | ((unsigned)hi[j + 1] << 16);
    *(unsigned*)(dst1 + byo) = (unsigned)lo[j] | ((unsigned)lo[j + 1] << 16);
  }
}

// ---------- split-bf16 MFMA GEMM (proven in R2) ----------
// EPI: 0 = C = acc + bias; 1 = C += acc; 2 = C = relu(C + acc)
template <int KA, int NB, int EPI>
__global__ __launch_bounds__(256) void k_gemm_mfma(
    const float* __restrict__ A, const unsigned short* __restrict__ Bimg,
    const float* __restrict__ bias, float* __restrict__ C) {
  constexpr int NT = NB / 128;
  constexpr int NSTEP = KA / 32;
  __shared__ uint4 ldsbuf[2048];  // 32 KB
  char* lds = (char*)ldsbuf;
  char* Ah = lds;
  char* Al = lds + 8192;
  char* Bp = lds + 16384;

  int tid = threadIdx.x;
  int nwg = gridDim.x;
  int q = nwg >> 3, r = nwg & 7;
  int xcd = blockIdx.x & 7, bidx = blockIdx.x >> 3;
  int wg = (xcd < r ? xcd * (q + 1) : r * (q + 1) + (xcd - r) * q) + bidx;
  int nt = wg % NT;
  int mt = wg / NT;
  int m0 = mt * 128, n0 = nt * 128;

  int l = tid & 63, w = tid >> 6;
  int wm = (w >> 1) * 64, wn = (w & 1) * 64;
  int lrow = l & 15, lk16 = (l >> 4) * 16;

  f32x4 acc[4][4];
#pragma unroll
  for (int i = 0; i < 4; ++i)
#pragma unroll
    for (int j = 0; j < 4; ++j)
#pragma unroll
      for (int cc = 0; cc < 4; ++cc) acc[i][j][cc] = 0.f;

  int srow = tid >> 1;
  int shalf = tid & 1;

  for (int kt = 0; kt < NSTEP; ++kt) {
    __syncthreads();
    {  // A stage: f32 -> split hi/lo, swizzled ds_write
      int gm = m0 + srow;
      const float* src = A + (size_t)gm * KA + kt * 32 + shalf * 16;
      int swz = (srow & 7) << 4;
      int b0 = srow * 64 + shalf * 32;
#pragma unroll
      for (int qd = 0; qd < 4; ++qd) {
        float4 v = make_float4(0.f, 0.f, 0.f, 0.f);
        if (gm < N_NODES) v = *(const float4*)(src + qd * 4);
        unsigned short h0 = f2bf(v.x), h1 = f2bf(v.y), h2 = f2bf(v.z), h3 = f2bf(v.w);
        unsigned short g0 = f2bf(v.x - bf2f(h0)), g1 = f2bf(v.y - bf2f(h1));
        unsigned short g2 = f2bf(v.z - bf2f(h2)), g3 = f2bf(v.w - bf2f(h3));
        int byo = (b0 + qd * 8) ^ swz;
        *(uint2*)(Ah + byo) = make_uint2((unsigned)h0 | ((unsigned)h1 << 16),
                                         (unsigned)h2 | ((unsigned)h3 << 16));
        *(uint2*)(Al + byo) = make_uint2((unsigned)g0 | ((unsigned)g1 << 16),
                                         (unsigned)g2 | ((unsigned)g3 << 16));
      }
    }
    {  // B copy: 16 KB pre-swizzled slab
      const char* bsrc = (const char*)Bimg + ((size_t)(kt * NT + nt)) * 16384;
#pragma unroll
      for (int qd = 0; qd < 4; ++qd) {
        int c = tid + qd * 256;
        *(uint4*)(Bp + c * 16) = *(const uint4*)(bsrc + c * 16);
      }
    }
    __syncthreads();

    bf16x8 ahf[4], alf[4], bhf[4], blf[4];
#pragma unroll
    for (int i = 0; i < 4; ++i) {
      int row = wm + i * 16 + lrow;
      int byo = (row * 64 + lk16) ^ ((row & 7) << 4);
      ahf[i] = *(bf16x8*)(Ah + byo);
      alf[i] = *(bf16x8*)(Al + byo);
    }
#pragma unroll
    for (int j = 0; j < 4; ++j) {
      int row = wn + j * 16 + lrow;
      int byo = (row * 64 + lk16) ^ ((row & 7) << 4);
      bhf[j] = *(bf16x8*)(Bp + byo);
      blf[j] = *(bf16x8*)(Bp + 8192 + byo);
    }
#pragma unroll
    for (int i = 0; i < 4; ++i)
#pragma unroll
      for (int j = 0; j < 4; ++j) {
        acc[i][j] = __builtin_amdgcn_mfma_f32_16x16x32_bf16(ahf[i], bhf[j], acc[i][j], 0, 0, 0);
        acc[i][j] = __builtin_amdgcn_mfma_f32_16x16x32_bf16(ahf[i], blf[j], acc[i][j], 0, 0, 0);
        acc[i][j] = __builtin_amdgcn_mfma_f32_16x16x32_bf16(alf[i], bhf[j], acc[i][j], 0, 0, 0);
      }
  }

#pragma unroll
  for (int j = 0; j < 4; ++j) {
    int colg = n0 + wn + j * 16 + lrow;
    float bj = (EPI == 0) ? bias[colg] : 0.f;
#pragma unroll
    for (int i = 0; i < 4; ++i) {
      int rbase = m0 + wm + i * 16 + (l >> 4) * 4;
#pragma unroll
      for (int reg = 0; reg < 4; ++reg) {
        int gm = rbase + reg;
        if (gm >= N_NODES) continue;
        size_t idx2 = (size_t)gm * NB + colg;
        float v = acc[i][j][reg];
        if (EPI == 0) v += bj;
        else v += C[idx2];
        if (EPI == 2) v = fmaxf(v, 0.f);
        C[idx2] = v;
      }
    }
  }
}

// ---------- batch-norm ----------
__global__ __launch_bounds__(256) void k_bnstats(const float* __restrict__ h,
                                                 double* __restrict__ stats) {
  int c = threadIdx.x & 127;
  int half = threadIdx.x >> 7;
  double s = 0.0, sq = 0.0;
  for (int row = blockIdx.x * 2 + half; row < N_NODES; row += gridDim.x * 2) {
    float v = h[(size_t)row * K_DIM + c];
    s += v;
    sq += (double)v * v;
  }
  __shared__ double sh[256];
  sh[threadIdx.x] = s;
  __syncthreads();
  if (half == 0) atomicAdd(&stats[c], s + sh[threadIdx.x + 128]);
  __syncthreads();
  sh[threadIdx.x] = sq;
  __syncthreads();
  if (half == 0) atomicAdd(&stats[128 + c], sq + sh[threadIdx.x + 128]);
}

__global__ void k_bnfin(const double* __restrict__ stats,
                        const float* __restrict__ normparams,
                        float* __restrict__ fstats) {
  int c = threadIdx.x;
  double s = stats[c], sq = stats[128 + c];
  double mean = s / N_NODES;
  double var = (sq - mean * mean * N_NODES) / (N_NODES - 1);
  float gamma = normparams[0];
  fstats[c] = (float)mean;
  fstats[128 + c] = (float)((double)gamma / sqrt(var + EPS));
}

__global__ __launch_bounds__(256) void k_bnapply(
    float* __restrict__ h, const float* __restrict__ fstats,
    const float* __restrict__ normparams) {
  int idx = blockIdx.x * 256 + threadIdx.x;
  if (idx >= N_NODES * 32) return;
  float beta = normparams[1];
  float4 v = ((float4*)h)[idx];
  int c4 = (idx & 31) * 4;
  v.x = (v.x - fstats[c4 + 0]) * fstats[128 + c4 + 0] + beta;
  v.y = (v.y - fstats[c4 + 1]) * fstats[128 + c4 + 1] + beta;
  v.z = (v.z - fstats[c4 + 2]) * fstats[128 + c4 + 2] + beta;
  v.w = (v.w - fstats[c4 + 3]) * fstats[128 + c4 + 3] + beta;
  ((float4*)h)[idx] = v;
}

extern "C" void kernel_launch(void* const* d_in, const int* in_sizes, int n_in,
                              void* d_out, int out_size, void* d_ws, size_t ws_size,
                              hipStream_t stream) {
  (void)in_sizes; (void)n_in; (void)out_size; (void)ws_size;
  const float* nodes = (const float*)d_in[0];
  const float* rels = (const float*)d_in[1];
  const float* W1 = (const float*)d_in[2];
  const float* b1 = (const float*)d_in[3];
  const float* W2 = (const float*)d_in[4];
  const float* b2 = (const float*)d_in[5];
  const float* normparams = (const float*)d_in[6];
  const int* froms = (const int*)d_in[7];
  const int* tos = (const int*)d_in[8];
  const int* relidx = (const int*)d_in[9];
  float* out = (float*)d_out;
  char* ws = (char*)d_ws;
  char* dob = (char*)d_out;

  // ---- ws layout (exactly the proven 210,003,072 B tier) ----
  float* nw_b = (float*)ws;                       // 102,400,000  [n][512] per batch
  float* h1 = (float*)(ws + 102400000);           // 102,400,000
  char* fix = ws + 204800000;
  float* denom = (float*)fix;                     // 1,600,000 (-> cursor)
  int* cursor = (int*)fix;
  unsigned* rowmax = (unsigned*)(fix + 1600000);  // 1,600,000 (-> W2s)
  unsigned short* W2s = (unsigned short*)(fix + 1600000);
  double* stats = (double*)(fix + 3200000);       //     2,048
  float* fstats = (float*)(fix + 3202048);        //     1,024
  float* att = (float*)(fix + 3203072);           // 2,000,000 (att -> ex -> vals)

  // ---- d_out scratch (all dead before GEMM2 overwrites d_out) ----
  unsigned short* W1s = (unsigned short*)dob;     // @0: 2,097,152
  int* row_ptr = (int*)(dob + 2097152);           // 1,600,004
  int* edge_order = (int*)(dob + 3700000);        // 2,000,000
  int* count = (int*)(dob + 5700000);             // 1,600,000
  int* aux = (int*)(dob + 7300000);               //     6,252

  hipMemsetAsync(fix, 0, 3202048, stream);        // denom, rowmax, stats
  hipMemsetAsync(count, 0, 1600000, stream);

  // edge pipeline
  k_edge_att<<<E_EDGES / 8, 256, 0, stream>>>(nodes, rels, froms, tos, relidx,
                                              att, rowmax);
  k_edge_exp_cnt<<<(E_EDGES + 255) / 256, 256, 0, stream>>>(froms, relidx,
                                                            rowmax, att, denom,
                                                            count);
  k_vals<<<(E_EDGES + 255) / 256, 256, 0, stream>>>(froms, relidx, denom, att);

  // CSR build (denom dead -> cursor; rowmax dead -> W2s after scan)
  k_scan1<<<SCAN_BLOCKS, 256, 0, stream>>>(count, aux);
  k_scan2<<<1, 256, 0, stream>>>(aux);
  k_scan3<<<SCAN_BLOCKS, 256, 0, stream>>>(count, aux, row_ptr, cursor);
  k_fill<<<(E_EDGES + 255) / 256, 256, 0, stream>>>(froms, relidx, cursor,
                                                    edge_order);

  // weight images
  k_prep_w<<<256, 256, 0, stream>>>(W1, W1s, 512, 4, 7);
  k_prep_w<<<32, 256, 0, stream>>>(W2, W2s, 128, 1, 6);

  // two relation batches of 4: gather -> GEMM1
  for (int b = 0; b < 2; ++b) {
    k_gather<<<25000, 256, 0, stream>>>(nodes, tos, att, row_ptr, edge_order,
                                        b * 200000, nw_b);
    const unsigned short* Bimg = W1s + (size_t)b * 524288;
    if (b == 0)
      k_gemm_mfma<512, 512, 0><<<1564, 256, 0, stream>>>(nw_b, Bimg, b1, h1);
    else
      k_gemm_mfma<512, 512, 2><<<1564, 256, 0, stream>>>(nw_b, Bimg, b1, h1);
  }

  // GEMM2: out = h1 @ W2 + b2 (overwrites all d_out scratch)
  k_gemm_mfma<512, 128, 0><<<391, 256, 0, stream>>>(h1, W2s, b2, out);

  k_bnstats<<<256, 256, 0, stream>>>(out, stats);
  k_bnfin<<<1, 128, 0, stream>>>(stats, normparams, fstats);
  k_bnapply<<<(N_NODES * 32 + 255) / 256, 256, 0, stream>>>(out, fstats,
                                                            normparams);
}

// Round 7
// 686.026 us; speedup vs baseline: 3.0868x; 1.1571x over previous
//
#include <hip/hip_runtime.h>
#include <math.h>

#define N_NODES 50000
#define K_DIM 128
#define R_REL 8
#define E_EDGES 500000
#define NROWS 400000      // N_NODES * R_REL
#define SCAN_BLOCKS 1563  // ceil(NROWS/256)
#define MTILES 391        // ceil(N_NODES/128); 391*128 = 50048
#define EPS 1e-8

typedef short bf16x8 __attribute__((ext_vector_type(8)));
typedef float f32x4 __attribute__((ext_vector_type(4)));

// ---------- bf16 helpers (RNE) ----------
__device__ __forceinline__ unsigned short f2bf(float x) {
  unsigned u = __float_as_uint(x);
  u = u + 0x7FFFu + ((u >> 16) & 1u);
  return (unsigned short)(u >> 16);
}
__device__ __forceinline__ float bf2f(unsigned short h) {
  return __uint_as_float(((unsigned)h) << 16);
}

// ---------- async global->LDS (16B per lane, wave-uniform LDS base) ----------
__device__ __forceinline__ void gload16(const void* g, void* l) {
  __builtin_amdgcn_global_load_lds(
      (const __attribute__((address_space(1))) void*)g,
      (__attribute__((address_space(3))) void*)l, 16, 0, 0);
}

// ---------- order-preserving float<->uint encoding for atomicMax ----------
__device__ __forceinline__ unsigned enc_f32(float f) {
  unsigned u = __float_as_uint(f);
  return (u & 0x80000000u) ? ~u : (u | 0x80000000u);
}
__device__ __forceinline__ float dec_f32(unsigned u) {
  unsigned v = (u & 0x80000000u) ? (u ^ 0x80000000u) : ~u;
  return __uint_as_float(v);
}

// ---------- kernel 1: per-edge attention logits + segment max ----------
__global__ __launch_bounds__(256) void k_edge_att(
    const float* __restrict__ nodes, const float* __restrict__ rels,
    const int* __restrict__ froms, const int* __restrict__ tos,
    const int* __restrict__ relidx, float* __restrict__ att,
    unsigned* __restrict__ rowmax) {
  int e = blockIdx.x * 8 + (threadIdx.x >> 5);
  int lane = threadIdx.x & 31;
  int f = froms[e], t = tos[e], r = relidx[e];
  const float4 a = ((const float4*)(nodes + (size_t)f * K_DIM))[lane];
  const float4 b = ((const float4*)(nodes + (size_t)t * K_DIM))[lane];
  const float4 c = ((const float4*)(rels + (size_t)r * K_DIM))[lane];
  float s = a.x * b.x * c.x + a.y * b.y * c.y + a.z * b.z * c.z + a.w * b.w * c.w;
#pragma unroll
  for (int o = 16; o; o >>= 1) s += __shfl_xor(s, o);
  if (lane == 0) {
    att[e] = s;
    atomicMax(rowmax + (f + r * N_NODES), enc_f32(s));
  }
}

// ---------- kernel 2: exp(att - rowmax) + segment denom + row counts ----------
__global__ __launch_bounds__(256) void k_edge_exp_cnt(
    const int* __restrict__ froms, const int* __restrict__ relidx,
    const unsigned* __restrict__ rowmax, float* __restrict__ att_ex,
    float* __restrict__ denom, int* __restrict__ count) {
  int e = blockIdx.x * 256 + threadIdx.x;
  if (e >= E_EDGES) return;
  int row = froms[e] + relidx[e] * N_NODES;
  float m = dec_f32(rowmax[row]);
  float ex = expf(att_ex[e] - m);
  att_ex[e] = ex;
  atomicAdd(denom + row, ex);
  atomicAdd(count + row, 1);
}

// ---------- kernel 3: vals[e] = ex[e] / denom[row]  (in place) ----------
__global__ __launch_bounds__(256) void k_vals(
    const int* __restrict__ froms, const int* __restrict__ relidx,
    const float* __restrict__ denom, float* __restrict__ vals) {
  int e = blockIdx.x * 256 + threadIdx.x;
  if (e >= E_EDGES) return;
  int row = froms[e] + relidx[e] * N_NODES;
  vals[e] /= denom[row];
}

// ---------- CSR build: scan (3 kernels) + fill ----------
__global__ __launch_bounds__(256) void k_scan1(const int* __restrict__ count,
                                               int* __restrict__ aux) {
  __shared__ int sh[256];
  int i = blockIdx.x * 256 + threadIdx.x;
  sh[threadIdx.x] = (i < NROWS) ? count[i] : 0;
  __syncthreads();
  for (int s = 128; s; s >>= 1) {
    if (threadIdx.x < s) sh[threadIdx.x] += sh[threadIdx.x + s];
    __syncthreads();
  }
  if (threadIdx.x == 0) aux[blockIdx.x] = sh[0];
}

__global__ void k_scan2(int* __restrict__ aux) {  // single block
  __shared__ int sh[256];
  __shared__ int running;
  if (threadIdx.x == 0) running = 0;
  __syncthreads();
  for (int base = 0; base < SCAN_BLOCKS; base += 256) {
    int i = base + threadIdx.x;
    int v = (i < SCAN_BLOCKS) ? aux[i] : 0;
    sh[threadIdx.x] = v;
    __syncthreads();
    for (int off = 1; off < 256; off <<= 1) {
      int t = (threadIdx.x >= off) ? sh[threadIdx.x - off] : 0;
      __syncthreads();
      sh[threadIdx.x] += t;
      __syncthreads();
    }
    int incl = sh[threadIdx.x];
    if (i < SCAN_BLOCKS) aux[i] = incl - v + running;
    __syncthreads();
    if (threadIdx.x == 0) running += sh[255];
    __syncthreads();
  }
}

__global__ __launch_bounds__(256) void k_scan3(const int* __restrict__ count,
                                               const int* __restrict__ aux,
                                               int* __restrict__ row_ptr,
                                               int* __restrict__ cursor) {
  __shared__ int sh[256];
  int i = blockIdx.x * 256 + threadIdx.x;
  int v = (i < NROWS) ? count[i] : 0;
  sh[threadIdx.x] = v;
  __syncthreads();
  for (int off = 1; off < 256; off <<= 1) {
    int t = (threadIdx.x >= off) ? sh[threadIdx.x - off] : 0;
    __syncthreads();
    sh[threadIdx.x] += t;
    __syncthreads();
  }
  int excl = sh[threadIdx.x] - v + aux[blockIdx.x];
  if (i < NROWS) {
    row_ptr[i] = excl;
    cursor[i] = excl;
    if (i == NROWS - 1) row_ptr[NROWS] = excl + v;
  }
}

__global__ __launch_bounds__(256) void k_fill(
    const int* __restrict__ froms, const int* __restrict__ relidx,
    int* __restrict__ cursor, int* __restrict__ edge_order) {
  int e = blockIdx.x * 256 + threadIdx.x;
  if (e >= E_EDGES) return;
  int row = froms[e] + relidx[e] * N_NODES;
  int pos = atomicAdd(cursor + row, 1);
  edge_order[pos] = e;
}

// ---------- gather -> pre-split, pre-swizzled bf16 A-tile image ----------
// Aimg layout: [mt(391)][kt(16)][plane hi/lo][8192B tile]
// tile inner: byte = (row*64 + kin*2) ^ ((row&7)<<4), row = node&127, kin = k&31
// Covers rows 0..50047 (pad rows 50000..50047 written as zeros).
__global__ __launch_bounds__(256) void k_gather_bf(
    const float* __restrict__ nodes, const int* __restrict__ tos,
    const float* __restrict__ vals, const int* __restrict__ row_ptr,
    const int* __restrict__ edge_order, int rb0,
    unsigned short* __restrict__ Aimg) {
  int g = blockIdx.x * 8 + (threadIdx.x >> 5);  // 0..200191
  int lane = threadIdx.x & 31;
  int rl = g / 50048;        // relation within batch, 0..3
  int f = g - rl * 50048;    // padded node id, 0..50047
  float4 acc = make_float4(0.f, 0.f, 0.f, 0.f);
  if (f < N_NODES) {
    int row = (rb0 + rl) * N_NODES + f;
    int rp0 = row_ptr[row], rp1 = row_ptr[row + 1];
    for (int p = rp0; p < rp1; ++p) {
      int e = edge_order[p];
      float v = vals[e];
      const float4 nb = ((const float4*)(nodes + (size_t)tos[e] * K_DIM))[lane];
      acc.x += v * nb.x;
      acc.y += v * nb.y;
      acc.z += v * nb.z;
      acc.w += v * nb.w;
    }
  }
  unsigned short h0 = f2bf(acc.x), h1 = f2bf(acc.y), h2 = f2bf(acc.z), h3 = f2bf(acc.w);
  unsigned short g0 = f2bf(acc.x - bf2f(h0)), g1 = f2bf(acc.y - bf2f(h1));
  unsigned short g2 = f2bf(acc.z - bf2f(h2)), g3 = f2bf(acc.w - bf2f(h3));
  int kt = rl * 4 + (lane >> 3);        // k-tile within batch (K=512 -> 16)
  int kin2 = (lane & 7) * 8;            // 2*kin, kin = 4k-group within tile
  int mt = f >> 7, row = f & 127;
  char* tile = (char*)Aimg + ((size_t)(mt * 16 + kt)) * 16384;
  int byo = (row * 64 + kin2) ^ ((row & 7) << 4);
  *(uint2*)(tile + byo) = make_uint2((unsigned)h0 | ((unsigned)h1 << 16),
                                     (unsigned)h2 | ((unsigned)h3 << 16));
  *(uint2*)(tile + 8192 + byo) = make_uint2((unsigned)g0 | ((unsigned)g1 << 16),
                                            (unsigned)g2 | ((unsigned)g3 << 16));
}

// ---------- weight prep: W [K][Nw] f32 -> swizzled split-bf16 tile image ----------
__global__ __launch_bounds__(256) void k_prep_w(
    const float* __restrict__ W, unsigned short* __restrict__ img,
    int Nw, int NT, int S) {
  int g = blockIdx.x * 256 + threadIdx.x;
  int n = g >> S;
  int k8 = g & ((1 << S) - 1);
  int k = k8 * 8;
  if (n >= Nw) return;
  int ktile = k >> 5, kin = k & 31;
  int row = n & 127, ntl = n >> 7;
  char* dst0 = (char*)img + ((size_t)(ktile * NT + ntl) * 2) * 8192;
  char* dst1 = dst0 + 8192;
  int swz = (row & 7) << 4;
  unsigned short hi[8], lo[8];
#pragma unroll
  for (int j = 0; j < 8; ++j) {
    float x = W[(size_t)(k + j) * Nw + n];
    hi[j] = f2bf(x);
    lo[j] = f2bf(x - bf2f(hi[j]));
  }
#pragma unroll
  for (int j = 0; j < 8; j += 2) {
    int byo = (row * 64 + (kin + j) * 2) ^ swz;
    *(unsigned*)(dst0 + byo) = (unsigned)hi[j] | ((unsigned)hi[j + 1] << 16);
    *(unsigned*)(dst1 + byo) = (unsigned)lo[j] | ((unsigned)lo[j + 1] << 16);
  }
}

// ---------- GEMM1: pre-split A image x pre-split B image (m97-style) ----------
// h1[M,512] (+)= A[M,512] @ W1b[512,512]; EPI: 0 = acc+bias; 2 = relu(C+acc)
// Staging = 8x global_load_lds(16B)/thread per K-step; LDS linear copy of
// pre-swizzled tiles; ds_read applies the same swizzle (m201 both-sides).
template <int EPI>
__global__ __launch_bounds__(256) void k_gemm_pre(
    const unsigned short* __restrict__ Aimg,
    const unsigned short* __restrict__ Bimg,
    const float* __restrict__ bias, float* __restrict__ C) {
  __shared__ char lds[32768];  // Ah 8K | Al 8K | Bh 8K | Bl 8K

  int tid = threadIdx.x;
  int nwg = gridDim.x;
  int q = nwg >> 3, r = nwg & 7;
  int xcd = blockIdx.x & 7, bidx = blockIdx.x >> 3;
  int wg = (xcd < r ? xcd * (q + 1) : r * (q + 1) + (xcd - r) * q) + bidx;
  int nt = wg & 3;   // 4 n-tiles
  int mt = wg >> 2;
  int m0 = mt * 128, n0 = nt * 128;

  int l = tid & 63, w = tid >> 6;
  int wm = (w >> 1) * 64, wn = (w & 1) * 64;
  int lrow = l & 15, lk16 = (l >> 4) * 16;

  f32x4 acc[4][4];
#pragma unroll
  for (int i = 0; i < 4; ++i)
#pragma unroll
    for (int j = 0; j < 4; ++j)
#pragma unroll
      for (int cc = 0; cc < 4; ++cc) acc[i][j][cc] = 0.f;

  const char* Abase = (const char*)Aimg + (size_t)mt * 262144;  // 16 kt * 16KB

  for (int kt = 0; kt < 16; ++kt) {
    __syncthreads();  // previous compute done; LDS reusable
    {
      const char* src;
      char* dst;
      if (w < 2) {  // A slab: hi plane (w=0) / lo plane (w=1)
        src = Abase + (size_t)kt * 16384 + w * 8192;
        dst = lds + w * 8192;
      } else {  // B slab for (kt, nt): hi / lo
        src = (const char*)Bimg + ((size_t)(kt * 4 + nt)) * 16384 + (w - 2) * 8192;
        dst = lds + 16384 + (w - 2) * 8192;
      }
#pragma unroll
      for (int it = 0; it < 8; ++it)
        gload16(src + it * 1024 + l * 16, dst + it * 1024);
    }
    __syncthreads();  // compiler drains vmcnt(0) before barrier

    bf16x8 ahf[4], alf[4], bhf[4], blf[4];
#pragma unroll
    for (int i = 0; i < 4; ++i) {
      int row = wm + i * 16 + lrow;
      int byo = (row * 64 + lk16) ^ ((row & 7) << 4);
      ahf[i] = *(bf16x8*)(lds + byo);
      alf[i] = *(bf16x8*)(lds + 8192 + byo);
    }
#pragma unroll
    for (int j = 0; j < 4; ++j) {
      int row = wn + j * 16 + lrow;
      int byo = (row * 64 + lk16) ^ ((row & 7) << 4);
      bhf[j] = *(bf16x8*)(lds + 16384 + byo);
      blf[j] = *(bf16x8*)(lds + 24576 + byo);
    }
#pragma unroll
    for (int i = 0; i < 4; ++i)
#pragma unroll
      for (int j = 0; j < 4; ++j) {
        acc[i][j] = __builtin_amdgcn_mfma_f32_16x16x32_bf16(ahf[i], bhf[j], acc[i][j], 0, 0, 0);
        acc[i][j] = __builtin_amdgcn_mfma_f32_16x16x32_bf16(ahf[i], blf[j], acc[i][j], 0, 0, 0);
        acc[i][j] = __builtin_amdgcn_mfma_f32_16x16x32_bf16(alf[i], bhf[j], acc[i][j], 0, 0, 0);
      }
  }

#pragma unroll
  for (int j = 0; j < 4; ++j) {
    int colg = n0 + wn + j * 16 + lrow;
    float bj = (EPI == 0) ? bias[colg] : 0.f;
#pragma unroll
    for (int i = 0; i < 4; ++i) {
      int rbase = m0 + wm + i * 16 + (l >> 4) * 4;
#pragma unroll
      for (int reg = 0; reg < 4; ++reg) {
        int gm = rbase + reg;
        if (gm >= N_NODES) continue;
        size_t idx2 = (size_t)gm * 512 + colg;
        float v = acc[i][j][reg];
        if (EPI == 0) v += bj;
        else v += C[idx2];
        if (EPI == 2) v = fmaxf(v, 0.f);
        C[idx2] = v;
      }
    }
  }
}

// ---------- GEMM2 (reg-staged f32 A, proven): C = A[M,KA]@Bimg + bias ----------
template <int KA, int NB, int EPI>
__global__ __launch_bounds__(256) void k_gemm_mfma(
    const float* __restrict__ A, const unsigned short* __restrict__ Bimg,
    const float* __restrict__ bias, float* __restrict__ C) {
  constexpr int NT = NB / 128;
  constexpr int NSTEP = KA / 32;
  __shared__ uint4 ldsbuf[2048];  // 32 KB
  char* lds = (char*)ldsbuf;
  char* Ah = lds;
  char* Al = lds + 8192;
  char* Bp = lds + 16384;

  int tid = threadIdx.x;
  int nwg = gridDim.x;
  int q = nwg >> 3, r = nwg & 7;
  int xcd = blockIdx.x & 7, bidx = blockIdx.x >> 3;
  int wg = (xcd < r ? xcd * (q + 1) : r * (q + 1) + (xcd - r) * q) + bidx;
  int nt = wg % NT;
  int mt = wg / NT;
  int m0 = mt * 128, n0 = nt * 128;

  int l = tid & 63, w = tid >> 6;
  int wm = (w >> 1) * 64, wn = (w & 1) * 64;
  int lrow = l & 15, lk16 = (l >> 4) * 16;

  f32x4 acc[4][4];
#pragma unroll
  for (int i = 0; i < 4; ++i)
#pragma unroll
    for (int j = 0; j < 4; ++j)
#pragma unroll
      for (int cc = 0; cc < 4; ++cc) acc[i][j][cc] = 0.f;

  int srow = tid >> 1;
  int shalf = tid & 1;

  for (int kt = 0; kt < NSTEP; ++kt) {
    __syncthreads();
    {  // A stage: f32 -> split hi/lo, swizzled ds_write
      int gm = m0 + srow;
      const float* src = A + (size_t)gm * KA + kt * 32 + shalf * 16;
      int swz = (srow & 7) << 4;
      int b0 = srow * 64 + shalf * 32;
#pragma unroll
      for (int qd = 0; qd < 4; ++qd) {
        float4 v = make_float4(0.f, 0.f, 0.f, 0.f);
        if (gm < N_NODES) v = *(const float4*)(src + qd * 4);
        unsigned short h0 = f2bf(v.x), h1 = f2bf(v.y), h2 = f2bf(v.z), h3 = f2bf(v.w);
        unsigned short g0 = f2bf(v.x - bf2f(h0)), g1 = f2bf(v.y - bf2f(h1));
        unsigned short g2 = f2bf(v.z - bf2f(h2)), g3 = f2bf(v.w - bf2f(h3));
        int byo = (b0 + qd * 8) ^ swz;
        *(uint2*)(Ah + byo) = make_uint2((unsigned)h0 | ((unsigned)h1 << 16),
                                         (unsigned)h2 | ((unsigned)h3 << 16));
        *(uint2*)(Al + byo) = make_uint2((unsigned)g0 | ((unsigned)g1 << 16),
                                         (unsigned)g2 | ((unsigned)g3 << 16));
      }
    }
    {  // B copy: 16 KB pre-swizzled slab
      const char* bsrc = (const char*)Bimg + ((size_t)(kt * NT + nt)) * 16384;
#pragma unroll
      for (int qd = 0; qd < 4; ++qd) {
        int c = tid + qd * 256;
        *(uint4*)(Bp + c * 16) = *(const uint4*)(bsrc + c * 16);
      }
    }
    __syncthreads();

    bf16x8 ahf[4], alf[4], bhf[4], blf[4];
#pragma unroll
    for (int i = 0; i < 4; ++i) {
      int row = wm + i * 16 + lrow;
      int byo = (row * 64 + lk16) ^ ((row & 7) << 4);
      ahf[i] = *(bf16x8*)(Ah + byo);
      alf[i] = *(bf16x8*)(Al + byo);
    }
#pragma unroll
    for (int j = 0; j < 4; ++j) {
      int row = wn + j * 16 + lrow;
      int byo = (row * 64 + lk16) ^ ((row & 7) << 4);
      bhf[j] = *(bf16x8*)(Bp + byo);
      blf[j] = *(bf16x8*)(Bp + 8192 + byo);
    }
#pragma unroll
    for (int i = 0; i < 4; ++i)
#pragma unroll
      for (int j = 0; j < 4; ++j) {
        acc[i][j] = __builtin_amdgcn_mfma_f32_16x16x32_bf16(ahf[i], bhf[j], acc[i][j], 0, 0, 0);
        acc[i][j] = __builtin_amdgcn_mfma_f32_16x16x32_bf16(ahf[i], blf[j], acc[i][j], 0, 0, 0);
        acc[i][j] = __builtin_amdgcn_mfma_f32_16x16x32_bf16(alf[i], bhf[j], acc[i][j], 0, 0, 0);
      }
  }

#pragma unroll
  for (int j = 0; j < 4; ++j) {
    int colg = n0 + wn + j * 16 + lrow;
    float bj = (EPI == 0) ? bias[colg] : 0.f;
#pragma unroll
    for (int i = 0; i < 4; ++i) {
      int rbase = m0 + wm + i * 16 + (l >> 4) * 4;
#pragma unroll
      for (int reg = 0; reg < 4; ++reg) {
        int gm = rbase + reg;
        if (gm >= N_NODES) continue;
        size_t idx2 = (size_t)gm * NB + colg;
        float v = acc[i][j][reg];
        if (EPI == 0) v += bj;
        else v += C[idx2];
        if (EPI == 2) v = fmaxf(v, 0.f);
        C[idx2] = v;
      }
    }
  }
}

// ---------- batch-norm ----------
__global__ __launch_bounds__(256) void k_bnstats(const float* __restrict__ h,
                                                 double* __restrict__ stats) {
  int c = threadIdx.x & 127;
  int half = threadIdx.x >> 7;
  double s = 0.0, sq = 0.0;
  for (int row = blockIdx.x * 2 + half; row < N_NODES; row += gridDim.x * 2) {
    float v = h[(size_t)row * K_DIM + c];
    s += v;
    sq += (double)v * v;
  }
  __shared__ double sh[256];
  sh[threadIdx.x] = s;
  __syncthreads();
  if (half == 0) atomicAdd(&stats[c], s + sh[threadIdx.x + 128]);
  __syncthreads();
  sh[threadIdx.x] = sq;
  __syncthreads();
  if (half == 0) atomicAdd(&stats[128 + c], sq + sh[threadIdx.x + 128]);
}

__global__ void k_bnfin(const double* __restrict__ stats,
                        const float* __restrict__ normparams,
                        float* __restrict__ fstats) {
  int c = threadIdx.x;
  double s = stats[c], sq = stats[128 + c];
  double mean = s / N_NODES;
  double var = (sq - mean * mean * N_NODES) / (N_NODES - 1);
  float gamma = normparams[0];
  fstats[c] = (float)mean;
  fstats[128 + c] = (float)((double)gamma / sqrt(var + EPS));
}

__global__ __launch_bounds__(256) void k_bnapply(
    float* __restrict__ h, const float* __restrict__ fstats,
    const float* __restrict__ normparams) {
  int idx = blockIdx.x * 256 + threadIdx.x;
  if (idx >= N_NODES * 32) return;
  float beta = normparams[1];
  float4 v = ((float4*)h)[idx];
  int c4 = (idx & 31) * 4;
  v.x = (v.x - fstats[c4 + 0]) * fstats[128 + c4 + 0] + beta;
  v.y = (v.y - fstats[c4 + 1]) * fstats[128 + c4 + 1] + beta;
  v.z = (v.z - fstats[c4 + 2]) * fstats[128 + c4 + 2] + beta;
  v.w = (v.w - fstats[c4 + 3]) * fstats[128 + c4 + 3] + beta;
  ((float4*)h)[idx] = v;
}

extern "C" void kernel_launch(void* const* d_in, const int* in_sizes, int n_in,
                              void* d_out, int out_size, void* d_ws, size_t ws_size,
                              hipStream_t stream) {
  (void)in_sizes; (void)n_in; (void)out_size; (void)ws_size;
  const float* nodes = (const float*)d_in[0];
  const float* rels = (const float*)d_in[1];
  const float* W1 = (const float*)d_in[2];
  const float* b1 = (const float*)d_in[3];
  const float* W2 = (const float*)d_in[4];
  const float* b2 = (const float*)d_in[5];
  const float* normparams = (const float*)d_in[6];
  const int* froms = (const int*)d_in[7];
  const int* tos = (const int*)d_in[8];
  const int* relidx = (const int*)d_in[9];
  float* out = (float*)d_out;
  char* ws = (char*)d_ws;
  char* dob = (char*)d_out;

  // ---- ws layout (205,163,520 B < proven 210,003,072 tier) ----
  unsigned short* Aimg = (unsigned short*)ws;          // 102,498,304 (391*16*2*8192)
  float* h1 = (float*)(ws + 102498304);                // 102,400,000
  unsigned short* W2s = (unsigned short*)(ws + 204898304);  // 262,144
  double* stats = (double*)(ws + 205160448);           //     2,048
  float* fstats = (float*)(ws + 205162496);            //     1,024

  // ---- d_out scratch (all dead before GEMM2 overwrites d_out) ----
  unsigned short* W1s = (unsigned short*)dob;          // @0: 2,097,152
  int* row_ptr = (int*)(dob + 2097152);                // 1,600,004
  int* edge_order = (int*)(dob + 3700000);             // 2,000,000
  int* count = (int*)(dob + 5700000);                  // 1,600,000
  int* aux = (int*)(dob + 7300000);                    //     6,252
  float* denom = (float*)(dob + 7310000);              // 1,600,000 (-> cursor)
  int* cursor = (int*)(dob + 7310000);
  unsigned* rowmax = (unsigned*)(dob + 8910000);       // 1,600,000
  float* att = (float*)(dob + 10510000);               // 2,000,000 (att->ex->vals)

  hipMemsetAsync(dob + 7310000, 0, 3200000, stream);   // denom + rowmax
  hipMemsetAsync(dob + 5700000, 0, 1600000, stream);   // count
  hipMemsetAsync(ws + 205160448, 0, 2048, stream);     // stats

  // edge pipeline
  k_edge_att<<<E_EDGES / 8, 256, 0, stream>>>(nodes, rels, froms, tos, relidx,
                                              att, rowmax);
  k_edge_exp_cnt<<<(E_EDGES + 255) / 256, 256, 0, stream>>>(froms, relidx,
                                                            rowmax, att, denom,
                                                            count);
  k_vals<<<(E_EDGES + 255) / 256, 256, 0, stream>>>(froms, relidx, denom, att);

  // CSR build
  k_scan1<<<SCAN_BLOCKS, 256, 0, stream>>>(count, aux);
  k_scan2<<<1, 256, 0, stream>>>(aux);
  k_scan3<<<SCAN_BLOCKS, 256, 0, stream>>>(count, aux, row_ptr, cursor);
  k_fill<<<(E_EDGES + 255) / 256, 256, 0, stream>>>(froms, relidx, cursor,
                                                    edge_order);

  // weight images
  k_prep_w<<<256, 256, 0, stream>>>(W1, W1s, 512, 4, 7);
  k_prep_w<<<32, 256, 0, stream>>>(W2, W2s, 128, 1, 6);

  // two relation batches of 4: gather (pre-split A image) -> GEMM1
  for (int b = 0; b < 2; ++b) {
    k_gather_bf<<<25024, 256, 0, stream>>>(nodes, tos, att, row_ptr,
                                           edge_order, b * 4, Aimg);
    const unsigned short* Bimg = W1s + (size_t)b * 524288;
    if (b == 0)
      k_gemm_pre<0><<<1564, 256, 0, stream>>>(Aimg, Bimg, b1, h1);
    else
      k_gemm_pre<2><<<1564, 256, 0, stream>>>(Aimg, Bimg, b1, h1);
  }

  // GEMM2: out = h1 @ W2 + b2 (overwrites all d_out scratch)
  k_gemm_mfma<512, 128, 0><<<391, 256, 0, stream>>>(h1, W2s, b2, out);

  k_bnstats<<<256, 256, 0, stream>>>(out, stats);
  k_bnfin<<<1, 128, 0, stream>>>(stats, normparams, fstats);
  k_bnapply<<<(N_NODES * 32 + 255) / 256, 256, 0, stream>>>(out, fstats,
                                                            normparams);
}

// Round 10
// 627.207 us; speedup vs baseline: 3.3762x; 1.0938x over previous
//
#include <hip/hip_runtime.h>
#include <math.h>

#define N_NODES 50000
#define K_DIM 128
#define R_REL 8
#define E_EDGES 500000
#define NROWS 400000      // N_NODES * R_REL
#define SCAN_BLOCKS 1563  // ceil(NROWS/256)
#define EPS 1e-8

typedef short bf16x8 __attribute__((ext_vector_type(8)));
typedef float f32x4 __attribute__((ext_vector_type(4)));

// ---------- bf16 helpers (RNE) ----------
__device__ __forceinline__ unsigned short f2bf(float x) {
  unsigned u = __float_as_uint(x);
  u = u + 0x7FFFu + ((u >> 16) & 1u);
  return (unsigned short)(u >> 16);
}
__device__ __forceinline__ float bf2f(unsigned short h) {
  return __uint_as_float(((unsigned)h) << 16);
}

// ---------- async global->LDS (16B per lane, wave-uniform LDS base) ----------
__device__ __forceinline__ void gload16(const void* g, void* l) {
  __builtin_amdgcn_global_load_lds(
      (const __attribute__((address_space(1))) void*)g,
      (__attribute__((address_space(3))) void*)l, 16, 0, 0);
}

// ---------- order-preserving float<->uint encoding for atomicMax ----------
__device__ __forceinline__ unsigned enc_f32(float f) {
  unsigned u = __float_as_uint(f);
  return (u & 0x80000000u) ? ~u : (u | 0x80000000u);
}
__device__ __forceinline__ float dec_f32(unsigned u) {
  unsigned v = (u & 0x80000000u) ? (u ^ 0x80000000u) : ~u;
  return __uint_as_float(v);
}

// ---------- kernel 1: per-edge attention logits + segment max ----------
__global__ __launch_bounds__(256) void k_edge_att(
    const float* __restrict__ nodes, const float* __restrict__ rels,
    const int* __restrict__ froms, const int* __restrict__ tos,
    const int* __restrict__ relidx, float* __restrict__ att,
    unsigned* __restrict__ rowmax) {
  int e = blockIdx.x * 8 + (threadIdx.x >> 5);
  int lane = threadIdx.x & 31;
  int f = froms[e], t = tos[e], r = relidx[e];
  const float4 a = ((const float4*)(nodes + (size_t)f * K_DIM))[lane];
  const float4 b = ((const float4*)(nodes + (size_t)t * K_DIM))[lane];
  const float4 c = ((const float4*)(rels + (size_t)r * K_DIM))[lane];
  float s = a.x * b.x * c.x + a.y * b.y * c.y + a.z * b.z * c.z + a.w * b.w * c.w;
#pragma unroll
  for (int o = 16; o; o >>= 1) s += __shfl_xor(s, o);
  if (lane == 0) {
    att[e] = s;
    atomicMax(rowmax + (f + r * N_NODES), enc_f32(s));
  }
}

// ---------- kernel 2: exp(att - rowmax) + segment denom + row counts ----------
__global__ __launch_bounds__(256) void k_edge_exp_cnt(
    const int* __restrict__ froms, const int* __restrict__ relidx,
    const unsigned* __restrict__ rowmax, float* __restrict__ att_ex,
    float* __restrict__ denom, int* __restrict__ count) {
  int e = blockIdx.x * 256 + threadIdx.x;
  if (e >= E_EDGES) return;
  int row = froms[e] + relidx[e] * N_NODES;
  float m = dec_f32(rowmax[row]);
  float ex = expf(att_ex[e] - m);
  att_ex[e] = ex;
  atomicAdd(denom + row, ex);
  atomicAdd(count + row, 1);
}

// ---------- CSR build: scan (3 kernels) + fill ----------
__global__ __launch_bounds__(256) void k_scan1(const int* __restrict__ count,
                                               int* __restrict__ aux) {
  __shared__ int sh[256];
  int i = blockIdx.x * 256 + threadIdx.x;
  sh[threadIdx.x] = (i < NROWS) ? count[i] : 0;
  __syncthreads();
  for (int s = 128; s; s >>= 1) {
    if (threadIdx.x < s) sh[threadIdx.x] += sh[threadIdx.x + s];
    __syncthreads();
  }
  if (threadIdx.x == 0) aux[blockIdx.x] = sh[0];
}

__global__ void k_scan2(int* __restrict__ aux) {  // single block
  __shared__ int sh[256];
  __shared__ int running;
  if (threadIdx.x == 0) running = 0;
  __syncthreads();
  for (int base = 0; base < SCAN_BLOCKS; base += 256) {
    int i = base + threadIdx.x;
    int v = (i < SCAN_BLOCKS) ? aux[i] : 0;
    sh[threadIdx.x] = v;
    __syncthreads();
    for (int off = 1; off < 256; off <<= 1) {
      int t = (threadIdx.x >= off) ? sh[threadIdx.x - off] : 0;
      __syncthreads();
      sh[threadIdx.x] += t;
      __syncthreads();
    }
    int incl = sh[threadIdx.x];
    if (i < SCAN_BLOCKS) aux[i] = incl - v + running;
    __syncthreads();
    if (threadIdx.x == 0) running += sh[255];
    __syncthreads();
  }
}

__global__ __launch_bounds__(256) void k_scan3(const int* __restrict__ count,
                                               const int* __restrict__ aux,
                                               int* __restrict__ row_ptr,
                                               int* __restrict__ cursor) {
  __shared__ int sh[256];
  int i = blockIdx.x * 256 + threadIdx.x;
  int v = (i < NROWS) ? count[i] : 0;
  sh[threadIdx.x] = v;
  __syncthreads();
  for (int off = 1; off < 256; off <<= 1) {
    int t = (threadIdx.x >= off) ? sh[threadIdx.x - off] : 0;
    __syncthreads();
    sh[threadIdx.x] += t;
    __syncthreads();
  }
  int excl = sh[threadIdx.x] - v + aux[blockIdx.x];
  if (i < NROWS) {
    row_ptr[i] = excl;
    cursor[i] = excl;
    if (i == NROWS - 1) row_ptr[NROWS] = excl + v;
  }
}

__global__ __launch_bounds__(256) void k_fill(
    const int* __restrict__ froms, const int* __restrict__ relidx,
    int* __restrict__ cursor, int* __restrict__ edge_order) {
  int e = blockIdx.x * 256 + threadIdx.x;
  if (e >= E_EDGES) return;
  int row = froms[e] + relidx[e] * N_NODES;
  int pos = atomicAdd(cursor + row, 1);
  edge_order[pos] = e;
}

// ---------- gather (softmax-normalize fused) -> pre-split swizzled A image ----------
// Aimg layout: [mt(391)][kt(16)][plane hi/lo][8192B tile]
// tile inner: byte = (row*64 + kin*2) ^ ((row&7)<<4), row = node&127, kin = k&31
__global__ __launch_bounds__(256) void k_gather_bf(
    const float* __restrict__ nodes, const int* __restrict__ tos,
    const float* __restrict__ ex, const float* __restrict__ denom,
    const int* __restrict__ row_ptr, const int* __restrict__ edge_order,
    int rb0, unsigned short* __restrict__ Aimg) {
  int g = blockIdx.x * 8 + (threadIdx.x >> 5);  // 0..200191
  int lane = threadIdx.x & 31;
  int rl = g / 50048;        // relation within batch, 0..3
  int f = g - rl * 50048;    // padded node id, 0..50047
  float4 acc = make_float4(0.f, 0.f, 0.f, 0.f);
  if (f < N_NODES) {
    int row = (rb0 + rl) * N_NODES + f;
    int rp0 = row_ptr[row], rp1 = row_ptr[row + 1];
    float dr = (rp1 > rp0) ? denom[row] : 1.0f;
    for (int p = rp0; p < rp1; ++p) {
      int e = edge_order[p];
      float v = ex[e] / dr;
      const float4 nb = ((const float4*)(nodes + (size_t)tos[e] * K_DIM))[lane];
      acc.x += v * nb.x;
      acc.y += v * nb.y;
      acc.z += v * nb.z;
      acc.w += v * nb.w;
    }
  }
  unsigned short h0 = f2bf(acc.x), h1 = f2bf(acc.y), h2 = f2bf(acc.z), h3 = f2bf(acc.w);
  unsigned short g0 = f2bf(acc.x - bf2f(h0)), g1 = f2bf(acc.y - bf2f(h1));
  unsigned short g2 = f2bf(acc.z - bf2f(h2)), g3 = f2bf(acc.w - bf2f(h3));
  int kt = rl * 4 + (lane >> 3);        // k-tile within batch (K=512 -> 16)
  int kin2 = (lane & 7) * 8;            // byte offset of 4-elem group
  int mt = f >> 7, row = f & 127;
  char* tile = (char*)Aimg + ((size_t)(mt * 16 + kt)) * 16384;
  int byo = (row * 64 + kin2) ^ ((row & 7) << 4);
  *(uint2*)(tile + byo) = make_uint2((unsigned)h0 | ((unsigned)h1 << 16),
                                     (unsigned)h2 | ((unsigned)h3 << 16));
  *(uint2*)(tile + 8192 + byo) = make_uint2((unsigned)g0 | ((unsigned)g1 << 16),
                                            (unsigned)g2 | ((unsigned)g3 << 16));
}

// ---------- weight prep: W [K][Nw] f32 -> swizzled split-bf16 tile image ----------
__global__ __launch_bounds__(256) void k_prep_w(
    const float* __restrict__ W, unsigned short* __restrict__ img,
    int Nw, int NT, int S) {
  int g = blockIdx.x * 256 + threadIdx.x;
  int n = g >> S;
  int k8 = g & ((1 << S) - 1);
  int k = k8 * 8;
  if (n >= Nw) return;
  int ktile = k >> 5, kin = k & 31;
  int row = n & 127, ntl = n >> 7;
  char* dst0 = (char*)img + ((size_t)(ktile * NT + ntl) * 2) * 8192;
  char* dst1 = dst0 + 8192;
  int swz = (row & 7) << 4;
  unsigned short hi[8], lo[8];
#pragma unroll
  for (int j = 0; j < 8; ++j) {
    float x = W[(size_t)(k + j) * Nw + n];
    hi[j] = f2bf(x);
    lo[j] = f2bf(x - bf2f(hi[j]));
  }
#pragma unroll
  for (int j = 0; j < 8; j += 2) {
    int byo = (row * 64 + (kin + j) * 2) ^ swz;
    *(unsigned*)(dst0 + byo) = (unsigned)hi[j] | ((unsigned)hi[j + 1] << 16);
    *(unsigned*)(dst1 + byo) = (unsigned)lo[j] | ((unsigned)lo[j + 1] << 16);
  }
}

// ---------- GEMM1: count-robust overlapped pipeline ----------
// Per iter: vmcnt(0)+barrier (tile kt landed everywhere), then ISSUE tile kt+1
// loads into buf^1 and compute tile kt from buf — loads fly under compute.
// h1img (+)= Aimg @ W1b. EPI 0: image = acc + bias; EPI 2: image = relu(image + acc)
template <int EPI>
__global__ __launch_bounds__(256) void k_gemm1(
    const unsigned short* __restrict__ Aimg,
    const unsigned short* __restrict__ Bimg,
    const float* __restrict__ bias, unsigned short* __restrict__ h1img) {
  __shared__ char lds[65536];  // 2 buffers x (Ah 8K | Al 8K | Bh 8K | Bl 8K)

  int tid = threadIdx.x;
  int nwg = gridDim.x;
  int q = nwg >> 3, r = nwg & 7;
  int xcd = blockIdx.x & 7, bidx = blockIdx.x >> 3;
  int wg = (xcd < r ? xcd * (q + 1) : r * (q + 1) + (xcd - r) * q) + bidx;
  int nt = wg & 3;
  int mt = wg >> 2;
  int n0 = nt * 128;

  int l = tid & 63, w = tid >> 6;
  int wm = (w >> 1) * 64, wn = (w & 1) * 64;
  int lrow = l & 15, lk16 = (l >> 4) * 16;

  f32x4 acc[4][4];
#pragma unroll
  for (int i = 0; i < 4; ++i)
#pragma unroll
    for (int j = 0; j < 4; ++j)
#pragma unroll
      for (int cc = 0; cc < 4; ++cc) acc[i][j][cc] = 0.f;

  const char* Abase = (const char*)Aimg + (size_t)mt * 262144;

  auto stage = [&](int kt, int buf) {
    const char* src;
    char* dst;
    char* base = lds + buf * 32768;
    if (w < 2) {
      src = Abase + (size_t)kt * 16384 + w * 8192;
      dst = base + w * 8192;
    } else {
      src = (const char*)Bimg + ((size_t)(kt * 4 + nt)) * 16384 + (w - 2) * 8192;
      dst = base + 16384 + (w - 2) * 8192;
    }
#pragma unroll
    for (int it = 0; it < 8; ++it)
      gload16(src + it * 1024 + l * 16, dst + it * 1024);
  };

  stage(0, 0);  // prologue
  int cur = 0;
#pragma unroll
  for (int kt = 0; kt < 16; ++kt) {
    // tile kt fully landed (count-robust: drains everything incl. any spills)
    asm volatile("s_waitcnt vmcnt(0) lgkmcnt(0)" ::: "memory");
    __builtin_amdgcn_s_barrier();
    __builtin_amdgcn_sched_barrier(0);  // nothing (esp. stage loads) may hoist above
    if (kt < 15) stage(kt + 1, cur ^ 1);  // issue-early: flies under compute
    {
      char* base = lds + cur * 32768;
      bf16x8 ahf[4], alf[4], bhf[4], blf[4];
#pragma unroll
      for (int i = 0; i < 4; ++i) {
        int row = wm + i * 16 + lrow;
        int byo = (row * 64 + lk16) ^ ((row & 7) << 4);
        ahf[i] = *(bf16x8*)(base + byo);
        alf[i] = *(bf16x8*)(base + 8192 + byo);
      }
#pragma unroll
      for (int j = 0; j < 4; ++j) {
        int row = wn + j * 16 + lrow;
        int byo = (row * 64 + lk16) ^ ((row & 7) << 4);
        bhf[j] = *(bf16x8*)(base + 16384 + byo);
        blf[j] = *(bf16x8*)(base + 24576 + byo);
      }
#pragma unroll
      for (int i = 0; i < 4; ++i)
#pragma unroll
        for (int j = 0; j < 4; ++j) {
          acc[i][j] = __builtin_amdgcn_mfma_f32_16x16x32_bf16(ahf[i], bhf[j], acc[i][j], 0, 0, 0);
          acc[i][j] = __builtin_amdgcn_mfma_f32_16x16x32_bf16(ahf[i], blf[j], acc[i][j], 0, 0, 0);
          acc[i][j] = __builtin_amdgcn_mfma_f32_16x16x32_bf16(alf[i], bhf[j], acc[i][j], 0, 0, 0);
        }
    }
    __builtin_amdgcn_sched_barrier(0);  // compute pinned before next iter's wait
    cur ^= 1;
  }

  // epilogue: write split-bf16 swizzled h1 image (pad rows included, defined)
  char* tbase = (char*)h1img + (size_t)mt * 262144;
#pragma unroll
  for (int j = 0; j < 4; ++j) {
    int colg = n0 + wn + j * 16 + lrow;
    int ktile = colg >> 5, kin = colg & 31;
    char* tile = tbase + (size_t)ktile * 16384;
    float bj = (EPI == 0) ? bias[colg] : 0.f;
#pragma unroll
    for (int i = 0; i < 4; ++i) {
      int rb = wm + i * 16 + (l >> 4) * 4;
#pragma unroll
      for (int reg = 0; reg < 4; ++reg) {
        int rr = rb + reg;
        int byo = (rr * 64 + kin * 2) ^ ((rr & 7) << 4);
        float v = acc[i][j][reg];
        if (EPI == 0) {
          v += bj;
        } else {
          float old = bf2f(*(unsigned short*)(tile + byo)) +
                      bf2f(*(unsigned short*)(tile + 8192 + byo));
          v = fmaxf(old + v, 0.f);
        }
        unsigned short hh = f2bf(v);
        unsigned short ll = f2bf(v - bf2f(hh));
        *(unsigned short*)(tile + byo) = hh;
        *(unsigned short*)(tile + 8192 + byo) = ll;
      }
    }
  }
}

// ---------- GEMM2: same robust pipeline, NT=1, f32 output ----------
__global__ __launch_bounds__(256) void k_gemm2(
    const unsigned short* __restrict__ Aimg,
    const unsigned short* __restrict__ Bimg,
    const float* __restrict__ bias, float* __restrict__ C) {
  __shared__ char lds[65536];

  int tid = threadIdx.x;
  int nwg = gridDim.x;
  int q = nwg >> 3, r = nwg & 7;
  int xcd = blockIdx.x & 7, bidx = blockIdx.x >> 3;
  int mt = (xcd < r ? xcd * (q + 1) : r * (q + 1) + (xcd - r) * q) + bidx;
  int m0 = mt * 128;

  int l = tid & 63, w = tid >> 6;
  int wm = (w >> 1) * 64, wn = (w & 1) * 64;
  int lrow = l & 15, lk16 = (l >> 4) * 16;

  f32x4 acc[4][4];
#pragma unroll
  for (int i = 0; i < 4; ++i)
#pragma unroll
    for (int j = 0; j < 4; ++j)
#pragma unroll
      for (int cc = 0; cc < 4; ++cc) acc[i][j][cc] = 0.f;

  const char* Abase = (const char*)Aimg + (size_t)mt * 262144;

  auto stage = [&](int kt, int buf) {
    const char* src;
    char* dst;
    char* base = lds + buf * 32768;
    if (w < 2) {
      src = Abase + (size_t)kt * 16384 + w * 8192;
      dst = base + w * 8192;
    } else {
      src = (const char*)Bimg + (size_t)kt * 16384 + (w - 2) * 8192;
      dst = base + 16384 + (w - 2) * 8192;
    }
#pragma unroll
    for (int it = 0; it < 8; ++it)
      gload16(src + it * 1024 + l * 16, dst + it * 1024);
  };

  stage(0, 0);
  int cur = 0;
#pragma unroll
  for (int kt = 0; kt < 16; ++kt) {
    asm volatile("s_waitcnt vmcnt(0) lgkmcnt(0)" ::: "memory");
    __builtin_amdgcn_s_barrier();
    __builtin_amdgcn_sched_barrier(0);
    if (kt < 15) stage(kt + 1, cur ^ 1);
    {
      char* base = lds + cur * 32768;
      bf16x8 ahf[4], alf[4], bhf[4], blf[4];
#pragma unroll
      for (int i = 0; i < 4; ++i) {
        int row = wm + i * 16 + lrow;
        int byo = (row * 64 + lk16) ^ ((row & 7) << 4);
        ahf[i] = *(bf16x8*)(base + byo);
        alf[i] = *(bf16x8*)(base + 8192 + byo);
      }
#pragma unroll
      for (int j = 0; j < 4; ++j) {
        int row = wn + j * 16 + lrow;
        int byo = (row * 64 + lk16) ^ ((row & 7) << 4);
        bhf[j] = *(bf16x8*)(base + 16384 + byo);
        blf[j] = *(bf16x8*)(base + 24576 + byo);
      }
#pragma unroll
      for (int i = 0; i < 4; ++i)
#pragma unroll
        for (int j = 0; j < 4; ++j) {
          acc[i][j] = __builtin_amdgcn_mfma_f32_16x16x32_bf16(ahf[i], bhf[j], acc[i][j], 0, 0, 0);
          acc[i][j] = __builtin_amdgcn_mfma_f32_16x16x32_bf16(ahf[i], blf[j], acc[i][j], 0, 0, 0);
          acc[i][j] = __builtin_amdgcn_mfma_f32_16x16x32_bf16(alf[i], bhf[j], acc[i][j], 0, 0, 0);
        }
    }
    __builtin_amdgcn_sched_barrier(0);
    cur ^= 1;
  }

#pragma unroll
  for (int j = 0; j < 4; ++j) {
    int colg = wn + j * 16 + lrow;
    float bj = bias[colg];
#pragma unroll
    for (int i = 0; i < 4; ++i) {
      int rbase = m0 + wm + i * 16 + (l >> 4) * 4;
#pragma unroll
      for (int reg = 0; reg < 4; ++reg) {
        int gm = rbase + reg;
        if (gm >= N_NODES) continue;
        C[(size_t)gm * 128 + colg] = acc[i][j][reg] + bj;
      }
    }
  }
}

// ---------- batch-norm ----------
__global__ __launch_bounds__(256) void k_bnstats(const float* __restrict__ h,
                                                 double* __restrict__ stats) {
  int c = threadIdx.x & 127;
  int half = threadIdx.x >> 7;
  double s = 0.0, sq = 0.0;
  for (int row = blockIdx.x * 2 + half; row < N_NODES; row += gridDim.x * 2) {
    float v = h[(size_t)row * K_DIM + c];
    s += v;
    sq += (double)v * v;
  }
  __shared__ double sh[256];
  sh[threadIdx.x] = s;
  __syncthreads();
  if (half == 0) atomicAdd(&stats[c], s + sh[threadIdx.x + 128]);
  __syncthreads();
  sh[threadIdx.x] = sq;
  __syncthreads();
  if (half == 0) atomicAdd(&stats[128 + c], sq + sh[threadIdx.x + 128]);
}

__global__ void k_bnfin(const double* __restrict__ stats,
                        const float* __restrict__ normparams,
                        float* __restrict__ fstats) {
  int c = threadIdx.x;
  double s = stats[c], sq = stats[128 + c];
  double mean = s / N_NODES;
  double var = (sq - mean * mean * N_NODES) / (N_NODES - 1);
  float gamma = normparams[0];
  fstats[c] = (float)mean;
  fstats[128 + c] = (float)((double)gamma / sqrt(var + EPS));
}

__global__ __launch_bounds__(256) void k_bnapply(
    float* __restrict__ h, const float* __restrict__ fstats,
    const float* __restrict__ normparams) {
  int idx = blockIdx.x * 256 + threadIdx.x;
  if (idx >= N_NODES * 32) return;
  float beta = normparams[1];
  float4 v = ((float4*)h)[idx];
  int c4 = (idx & 31) * 4;
  v.x = (v.x - fstats[c4 + 0]) * fstats[128 + c4 + 0] + beta;
  v.y = (v.y - fstats[c4 + 1]) * fstats[128 + c4 + 1] + beta;
  v.z = (v.z - fstats[c4 + 2]) * fstats[128 + c4 + 2] + beta;
  v.w = (v.w - fstats[c4 + 3]) * fstats[128 + c4 + 3] + beta;
  ((float4*)h)[idx] = v;
}

extern "C" void kernel_launch(void* const* d_in, const int* in_sizes, int n_in,
                              void* d_out, int out_size, void* d_ws, size_t ws_size,
                              hipStream_t stream) {
  (void)in_sizes; (void)n_in; (void)out_size; (void)ws_size;
  const float* nodes = (const float*)d_in[0];
  const float* rels = (const float*)d_in[1];
  const float* W1 = (const float*)d_in[2];
  const float* b1 = (const float*)d_in[3];
  const float* W2 = (const float*)d_in[4];
  const float* b2 = (const float*)d_in[5];
  const float* normparams = (const float*)d_in[6];
  const int* froms = (const int*)d_in[7];
  const int* tos = (const int*)d_in[8];
  const int* relidx = (const int*)d_in[9];
  float* out = (float*)d_out;
  char* ws = (char*)d_ws;
  char* dob = (char*)d_out;

  // ---- ws layout (205,261,824 B < proven 210,003,072 tier) ----
  unsigned short* Aimg = (unsigned short*)ws;              // 102,498,304
  unsigned short* h1img = (unsigned short*)(ws + 102498304);  // 102,498,304
  unsigned short* W2s = (unsigned short*)(ws + 204996608);    //     262,144
  double* stats = (double*)(ws + 205258752);                  //       2,048
  float* fstats = (float*)(ws + 205260800);                   //       1,024

  // ---- d_out scratch (all dead before GEMM2 overwrites d_out) ----
  // NOTE: cursor gets its OWN region — denom must stay live for the gathers
  // (R8/R9 bug: cursor aliased denom and the CSR fill clobbered it).
  unsigned short* W1s = (unsigned short*)dob;          // @0: 2,097,152
  int* row_ptr = (int*)(dob + 2097152);                // 1,600,004
  int* edge_order = (int*)(dob + 3700000);             // 2,000,000
  int* count = (int*)(dob + 5700000);                  // 1,600,000
  int* aux = (int*)(dob + 7300000);                    //     6,252
  float* denom = (float*)(dob + 7310000);              // 1,600,000 (LIVE thru gathers)
  unsigned* rowmax = (unsigned*)(dob + 8910000);       // 1,600,000
  float* att = (float*)(dob + 10510000);               // 2,000,000 (att -> ex)
  int* cursor = (int*)(dob + 12510000);                // 1,600,000 (own region)

  hipMemsetAsync(dob + 7310000, 0, 3200000, stream);   // denom + rowmax
  hipMemsetAsync(dob + 5700000, 0, 1600000, stream);   // count
  hipMemsetAsync(ws + 205258752, 0, 2048, stream);     // stats

  // edge pipeline
  k_edge_att<<<E_EDGES / 8, 256, 0, stream>>>(nodes, rels, froms, tos, relidx,
                                              att, rowmax);
  k_edge_exp_cnt<<<(E_EDGES + 255) / 256, 256, 0, stream>>>(froms, relidx,
                                                            rowmax, att, denom,
                                                            count);

  // CSR build
  k_scan1<<<SCAN_BLOCKS, 256, 0, stream>>>(count, aux);
  k_scan2<<<1, 256, 0, stream>>>(aux);
  k_scan3<<<SCAN_BLOCKS, 256, 0, stream>>>(count, aux, row_ptr, cursor);
  k_fill<<<(E_EDGES + 255) / 256, 256, 0, stream>>>(froms, relidx, cursor,
                                                    edge_order);

  // weight images
  k_prep_w<<<256, 256, 0, stream>>>(W1, W1s, 512, 4, 7);
  k_prep_w<<<32, 256, 0, stream>>>(W2, W2s, 128, 1, 6);

  // two relation batches of 4: gather (div fused) -> pipelined GEMM1
  for (int b = 0; b < 2; ++b) {
    k_gather_bf<<<25024, 256, 0, stream>>>(nodes, tos, att, denom, row_ptr,
                                           edge_order, b * 4, Aimg);
    const unsigned short* Bimg = W1s + (size_t)b * 524288;
    if (b == 0)
      k_gemm1<0><<<1564, 256, 0, stream>>>(Aimg, Bimg, b1, h1img);
    else
      k_gemm1<2><<<1564, 256, 0, stream>>>(Aimg, Bimg, b1, h1img);
  }

  // GEMM2: out = h1 @ W2 + b2 (overwrites all d_out scratch)
  k_gemm2<<<391, 256, 0, stream>>>(h1img, W2s, b2, out);

  k_bnstats<<<256, 256, 0, stream>>>(out, stats);
  k_bnfin<<<1, 128, 0, stream>>>(stats, normparams, fstats);
  k_bnapply<<<(N_NODES * 32 + 255) / 256, 256, 0, stream>>>(out, fstats,
                                                            normparams);
}

// Round 11
// 538.209 us; speedup vs baseline: 3.9345x; 1.1654x over previous
//
#include <hip/hip_runtime.h>
#include <math.h>

#define N_NODES 50000
#define K_DIM 128
#define R_REL 8
#define E_EDGES 500000
#define NROWS 400000      // N_NODES * R_REL
#define SCAN_BLOCKS 1563  // ceil(NROWS/256)
#define EPS 1e-8

typedef short bf16x8 __attribute__((ext_vector_type(8)));
typedef float f32x4 __attribute__((ext_vector_type(4)));

// ---------- bf16 helpers (RNE) ----------
__device__ __forceinline__ unsigned short f2bf(float x) {
  unsigned u = __float_as_uint(x);
  u = u + 0x7FFFu + ((u >> 16) & 1u);
  return (unsigned short)(u >> 16);
}
__device__ __forceinline__ float bf2f(unsigned short h) {
  return __uint_as_float(((unsigned)h) << 16);
}

// ---------- async global->LDS (16B per lane, wave-uniform LDS base) ----------
__device__ __forceinline__ void gload16(const void* g, void* l) {
  __builtin_amdgcn_global_load_lds(
      (const __attribute__((address_space(1))) void*)g,
      (__attribute__((address_space(3))) void*)l, 16, 0, 0);
}

// ---------- order-preserving float<->uint encoding for atomicMax ----------
__device__ __forceinline__ unsigned enc_f32(float f) {
  unsigned u = __float_as_uint(f);
  return (u & 0x80000000u) ? ~u : (u | 0x80000000u);
}
__device__ __forceinline__ float dec_f32(unsigned u) {
  unsigned v = (u & 0x80000000u) ? (u ^ 0x80000000u) : ~u;
  return __uint_as_float(v);
}

// ---------- kernel 1: per-edge attention logits + segment max ----------
__global__ __launch_bounds__(256) void k_edge_att(
    const float* __restrict__ nodes, const float* __restrict__ rels,
    const int* __restrict__ froms, const int* __restrict__ tos,
    const int* __restrict__ relidx, float* __restrict__ att,
    unsigned* __restrict__ rowmax) {
  int e = blockIdx.x * 8 + (threadIdx.x >> 5);
  int lane = threadIdx.x & 31;
  int f = froms[e], t = tos[e], r = relidx[e];
  const float4 a = ((const float4*)(nodes + (size_t)f * K_DIM))[lane];
  const float4 b = ((const float4*)(nodes + (size_t)t * K_DIM))[lane];
  const float4 c = ((const float4*)(rels + (size_t)r * K_DIM))[lane];
  float s = a.x * b.x * c.x + a.y * b.y * c.y + a.z * b.z * c.z + a.w * b.w * c.w;
#pragma unroll
  for (int o = 16; o; o >>= 1) s += __shfl_xor(s, o);
  if (lane == 0) {
    att[e] = s;
    atomicMax(rowmax + (f + r * N_NODES), enc_f32(s));
  }
}

// ---------- kernel 2: exp(att - rowmax) + segment denom + row counts ----------
__global__ __launch_bounds__(256) void k_edge_exp_cnt(
    const int* __restrict__ froms, const int* __restrict__ relidx,
    const unsigned* __restrict__ rowmax, float* __restrict__ att_ex,
    float* __restrict__ denom, int* __restrict__ count) {
  int e = blockIdx.x * 256 + threadIdx.x;
  if (e >= E_EDGES) return;
  int row = froms[e] + relidx[e] * N_NODES;
  float m = dec_f32(rowmax[row]);
  float ex = expf(att_ex[e] - m);
  att_ex[e] = ex;
  atomicAdd(denom + row, ex);
  atomicAdd(count + row, 1);
}

// ---------- CSR build: scan (3 kernels) + fill ----------
__global__ __launch_bounds__(256) void k_scan1(const int* __restrict__ count,
                                               int* __restrict__ aux) {
  __shared__ int sh[256];
  int i = blockIdx.x * 256 + threadIdx.x;
  sh[threadIdx.x] = (i < NROWS) ? count[i] : 0;
  __syncthreads();
  for (int s = 128; s; s >>= 1) {
    if (threadIdx.x < s) sh[threadIdx.x] += sh[threadIdx.x + s];
    __syncthreads();
  }
  if (threadIdx.x == 0) aux[blockIdx.x] = sh[0];
}

__global__ void k_scan2(int* __restrict__ aux) {  // single block
  __shared__ int sh[256];
  __shared__ int running;
  if (threadIdx.x == 0) running = 0;
  __syncthreads();
  for (int base = 0; base < SCAN_BLOCKS; base += 256) {
    int i = base + threadIdx.x;
    int v = (i < SCAN_BLOCKS) ? aux[i] : 0;
    sh[threadIdx.x] = v;
    __syncthreads();
    for (int off = 1; off < 256; off <<= 1) {
      int t = (threadIdx.x >= off) ? sh[threadIdx.x - off] : 0;
      __syncthreads();
      sh[threadIdx.x] += t;
      __syncthreads();
    }
    int incl = sh[threadIdx.x];
    if (i < SCAN_BLOCKS) aux[i] = incl - v + running;
    __syncthreads();
    if (threadIdx.x == 0) running += sh[255];
    __syncthreads();
  }
}

__global__ __launch_bounds__(256) void k_scan3(const int* __restrict__ count,
                                               const int* __restrict__ aux,
                                               int* __restrict__ row_ptr,
                                               int* __restrict__ cursor) {
  __shared__ int sh[256];
  int i = blockIdx.x * 256 + threadIdx.x;
  int v = (i < NROWS) ? count[i] : 0;
  sh[threadIdx.x] = v;
  __syncthreads();
  for (int off = 1; off < 256; off <<= 1) {
    int t = (threadIdx.x >= off) ? sh[threadIdx.x - off] : 0;
    __syncthreads();
    sh[threadIdx.x] += t;
    __syncthreads();
  }
  int excl = sh[threadIdx.x] - v + aux[blockIdx.x];
  if (i < NROWS) {
    row_ptr[i] = excl;
    cursor[i] = excl;
    if (i == NROWS - 1) row_ptr[NROWS] = excl + v;
  }
}

__global__ __launch_bounds__(256) void k_fill(
    const int* __restrict__ froms, const int* __restrict__ relidx,
    int* __restrict__ cursor, int* __restrict__ edge_order) {
  int e = blockIdx.x * 256 + threadIdx.x;
  if (e >= E_EDGES) return;
  int row = froms[e] + relidx[e] * N_NODES;
  int pos = atomicAdd(cursor + row, 1);
  edge_order[pos] = e;
}

// ---------- gather (softmax-normalize fused) -> single-plane swizzled A image ----------
// Aimg layout: [mt(391)][kt(16)][8192B tile]
// tile inner: byte = (row*64 + kin*2) ^ ((row&7)<<4), row = node&127, kin = k&31
__global__ __launch_bounds__(256) void k_gather_bf(
    const float* __restrict__ nodes, const int* __restrict__ tos,
    const float* __restrict__ ex, const float* __restrict__ denom,
    const int* __restrict__ row_ptr, const int* __restrict__ edge_order,
    int rb0, unsigned short* __restrict__ Aimg) {
  int g = blockIdx.x * 8 + (threadIdx.x >> 5);  // 0..200191
  int lane = threadIdx.x & 31;
  int rl = g / 50048;        // relation within batch, 0..3
  int f = g - rl * 50048;    // padded node id, 0..50047
  float4 acc = make_float4(0.f, 0.f, 0.f, 0.f);
  if (f < N_NODES) {
    int row = (rb0 + rl) * N_NODES + f;
    int rp0 = row_ptr[row], rp1 = row_ptr[row + 1];
    float dr = (rp1 > rp0) ? denom[row] : 1.0f;
    for (int p = rp0; p < rp1; ++p) {
      int e = edge_order[p];
      float v = ex[e] / dr;
      const float4 nb = ((const float4*)(nodes + (size_t)tos[e] * K_DIM))[lane];
      acc.x += v * nb.x;
      acc.y += v * nb.y;
      acc.z += v * nb.z;
      acc.w += v * nb.w;
    }
  }
  unsigned short h0 = f2bf(acc.x), h1 = f2bf(acc.y), h2 = f2bf(acc.z), h3 = f2bf(acc.w);
  int kt = rl * 4 + (lane >> 3);        // k-tile within batch (K=512 -> 16)
  int kin2 = (lane & 7) * 8;            // byte offset of 4-elem group
  int mt = f >> 7, row = f & 127;
  char* tile = (char*)Aimg + ((size_t)(mt * 16 + kt)) * 8192;
  int byo = (row * 64 + kin2) ^ ((row & 7) << 4);
  *(uint2*)(tile + byo) = make_uint2((unsigned)h0 | ((unsigned)h1 << 16),
                                     (unsigned)h2 | ((unsigned)h3 << 16));
}

// ---------- weight prep: W [K][Nw] f32 -> swizzled split-bf16 tile image ----------
__global__ __launch_bounds__(256) void k_prep_w(
    const float* __restrict__ W, unsigned short* __restrict__ img,
    int Nw, int NT, int S) {
  int g = blockIdx.x * 256 + threadIdx.x;
  int n = g >> S;
  int k8 = g & ((1 << S) - 1);
  int k = k8 * 8;
  if (n >= Nw) return;
  int ktile = k >> 5, kin = k & 31;
  int row = n & 127, ntl = n >> 7;
  char* dst0 = (char*)img + ((size_t)(ktile * NT + ntl) * 2) * 8192;
  char* dst1 = dst0 + 8192;
  int swz = (row & 7) << 4;
  unsigned short hi[8], lo[8];
#pragma unroll
  for (int j = 0; j < 8; ++j) {
    float x = W[(size_t)(k + j) * Nw + n];
    hi[j] = f2bf(x);
    lo[j] = f2bf(x - bf2f(hi[j]));
  }
#pragma unroll
  for (int j = 0; j < 8; j += 2) {
    int byo = (row * 64 + (kin + j) * 2) ^ swz;
    *(unsigned*)(dst0 + byo) = (unsigned)hi[j] | ((unsigned)hi[j + 1] << 16);
    *(unsigned*)(dst1 + byo) = (unsigned)lo[j] | ((unsigned)lo[j + 1] << 16);
  }
}

// ---------- GEMM1: counted-vmcnt pipelined, A single-plane x W split ----------
// Per iter: issue stage(kt+1) -> vmcnt(6) (tile kt landed, kt+1 in flight a
// full iteration) -> barrier -> compute -> barrier.
// h1img (+)= Aimg @ W1b. EPI 0: image = acc + bias; EPI 2: image = relu(image + acc)
template <int EPI>
__global__ __launch_bounds__(256) void k_gemm1(
    const unsigned short* __restrict__ Aimg,
    const unsigned short* __restrict__ Bimg,
    const float* __restrict__ bias, unsigned short* __restrict__ h1img) {
  __shared__ char lds[49152];  // 2 buffers x (A 8K | Bh 8K | Bl 8K)

  int tid = threadIdx.x;
  int nwg = gridDim.x;
  int q = nwg >> 3, r = nwg & 7;
  int xcd = blockIdx.x & 7, bidx = blockIdx.x >> 3;
  int wg = (xcd < r ? xcd * (q + 1) : r * (q + 1) + (xcd - r) * q) + bidx;
  int nt = wg & 3;
  int mt = wg >> 2;
  int n0 = nt * 128;

  int l = tid & 63, w = tid >> 6;
  int wm = (w >> 1) * 64, wn = (w & 1) * 64;
  int lrow = l & 15, lk16 = (l >> 4) * 16;

  f32x4 acc[4][4];
#pragma unroll
  for (int i = 0; i < 4; ++i)
#pragma unroll
    for (int j = 0; j < 4; ++j)
#pragma unroll
      for (int cc = 0; cc < 4; ++cc) acc[i][j][cc] = 0.f;

  const char* Abase = (const char*)Aimg + (size_t)mt * 131072;  // 16 kt * 8KB

  auto stage = [&](int kt, int buf) {
    char* base = lds + buf * 24576;
    const char* asrc = Abase + (size_t)kt * 8192;
    const char* bsrc = (const char*)Bimg + ((size_t)(kt * 4 + nt)) * 16384;
#pragma unroll
    for (int c6 = 0; c6 < 6; ++c6) {
      int c = w * 6 + c6;
      const char* src = (c < 8) ? (asrc + c * 1024) : (bsrc + (c - 8) * 1024);
      gload16(src + l * 16, base + c * 1024);
    }
  };

  stage(0, 0);  // prologue
  int cur = 0;
#pragma unroll
  for (int kt = 0; kt < 16; ++kt) {
    if (kt < 15) {
      stage(kt + 1, cur ^ 1);  // issued BEFORE the wait: flies a full iteration
      asm volatile("s_waitcnt vmcnt(6)" ::: "memory");  // tile kt landed (6 newer ok)
    } else {
      asm volatile("s_waitcnt vmcnt(0)" ::: "memory");
    }
    __builtin_amdgcn_s_barrier();       // all waves have tile kt in LDS
    __builtin_amdgcn_sched_barrier(0);
    {
      char* base = lds + cur * 24576;
      bf16x8 ahf[4], bhf[4], blf[4];
#pragma unroll
      for (int i = 0; i < 4; ++i) {
        int row = wm + i * 16 + lrow;
        int byo = (row * 64 + lk16) ^ ((row & 7) << 4);
        ahf[i] = *(bf16x8*)(base + byo);
      }
#pragma unroll
      for (int j = 0; j < 4; ++j) {
        int row = wn + j * 16 + lrow;
        int byo = (row * 64 + lk16) ^ ((row & 7) << 4);
        bhf[j] = *(bf16x8*)(base + 8192 + byo);
        blf[j] = *(bf16x8*)(base + 16384 + byo);
      }
#pragma unroll
      for (int i = 0; i < 4; ++i)
#pragma unroll
        for (int j = 0; j < 4; ++j) {
          acc[i][j] = __builtin_amdgcn_mfma_f32_16x16x32_bf16(ahf[i], bhf[j], acc[i][j], 0, 0, 0);
          acc[i][j] = __builtin_amdgcn_mfma_f32_16x16x32_bf16(ahf[i], blf[j], acc[i][j], 0, 0, 0);
        }
    }
    __builtin_amdgcn_sched_barrier(0);
    __builtin_amdgcn_s_barrier();  // all reads of cur done before buf^1... (next overwrite of cur)
    cur ^= 1;
  }

  // epilogue: write single-plane bf16 swizzled h1 image (pad rows defined)
  char* tbase = (char*)h1img + (size_t)mt * 131072;
#pragma unroll
  for (int j = 0; j < 4; ++j) {
    int colg = n0 + wn + j * 16 + lrow;
    int ktile = colg >> 5, kin = colg & 31;
    char* tile = tbase + (size_t)ktile * 8192;
    float bj = (EPI == 0) ? bias[colg] : 0.f;
#pragma unroll
    for (int i = 0; i < 4; ++i) {
      int rb = wm + i * 16 + (l >> 4) * 4;
#pragma unroll
      for (int reg = 0; reg < 4; ++reg) {
        int rr = rb + reg;
        int byo = (rr * 64 + kin * 2) ^ ((rr & 7) << 4);
        float v = acc[i][j][reg];
        if (EPI == 0) {
          v += bj;
        } else {
          float old = bf2f(*(unsigned short*)(tile + byo));
          v = fmaxf(old + v, 0.f);
        }
        *(unsigned short*)(tile + byo) = f2bf(v);
      }
    }
  }
}

// ---------- GEMM2: same pipeline, NT=1, f32 output ----------
__global__ __launch_bounds__(256) void k_gemm2(
    const unsigned short* __restrict__ Aimg,
    const unsigned short* __restrict__ Bimg,
    const float* __restrict__ bias, float* __restrict__ C) {
  __shared__ char lds[49152];

  int tid = threadIdx.x;
  int nwg = gridDim.x;
  int q = nwg >> 3, r = nwg & 7;
  int xcd = blockIdx.x & 7, bidx = blockIdx.x >> 3;
  int mt = (xcd < r ? xcd * (q + 1) : r * (q + 1) + (xcd - r) * q) + bidx;
  int m0 = mt * 128;

  int l = tid & 63, w = tid >> 6;
  int wm = (w >> 1) * 64, wn = (w & 1) * 64;
  int lrow = l & 15, lk16 = (l >> 4) * 16;

  f32x4 acc[4][4];
#pragma unroll
  for (int i = 0; i < 4; ++i)
#pragma unroll
    for (int j = 0; j < 4; ++j)
#pragma unroll
      for (int cc = 0; cc < 4; ++cc) acc[i][j][cc] = 0.f;

  const char* Abase = (const char*)Aimg + (size_t)mt * 131072;

  auto stage = [&](int kt, int buf) {
    char* base = lds + buf * 24576;
    const char* asrc = Abase + (size_t)kt * 8192;
    const char* bsrc = (const char*)Bimg + (size_t)kt * 16384;
#pragma unroll
    for (int c6 = 0; c6 < 6; ++c6) {
      int c = w * 6 + c6;
      const char* src = (c < 8) ? (asrc + c * 1024) : (bsrc + (c - 8) * 1024);
      gload16(src + l * 16, base + c * 1024);
    }
  };

  stage(0, 0);
  int cur = 0;
#pragma unroll
  for (int kt = 0; kt < 16; ++kt) {
    if (kt < 15) {
      stage(kt + 1, cur ^ 1);
      asm volatile("s_waitcnt vmcnt(6)" ::: "memory");
    } else {
      asm volatile("s_waitcnt vmcnt(0)" ::: "memory");
    }
    __builtin_amdgcn_s_barrier();
    __builtin_amdgcn_sched_barrier(0);
    {
      char* base = lds + cur * 24576;
      bf16x8 ahf[4], bhf[4], blf[4];
#pragma unroll
      for (int i = 0; i < 4; ++i) {
        int row = wm + i * 16 + lrow;
        int byo = (row * 64 + lk16) ^ ((row & 7) << 4);
        ahf[i] = *(bf16x8*)(base + byo);
      }
#pragma unroll
      for (int j = 0; j < 4; ++j) {
        int row = wn + j * 16 + lrow;
        int byo = (row * 64 + lk16) ^ ((row & 7) << 4);
        bhf[j] = *(bf16x8*)(base + 8192 + byo);
        blf[j] = *(bf16x8*)(base + 16384 + byo);
      }
#pragma unroll
      for (int i = 0; i < 4; ++i)
#pragma unroll
        for (int j = 0; j < 4; ++j) {
          acc[i][j] = __builtin_amdgcn_mfma_f32_16x16x32_bf16(ahf[i], bhf[j], acc[i][j], 0, 0, 0);
          acc[i][j] = __builtin_amdgcn_mfma_f32_16x16x32_bf16(ahf[i], blf[j], acc[i][j], 0, 0, 0);
        }
    }
    __builtin_amdgcn_sched_barrier(0);
    __builtin_amdgcn_s_barrier();
    cur ^= 1;
  }

#pragma unroll
  for (int j = 0; j < 4; ++j) {
    int colg = wn + j * 16 + lrow;
    float bj = bias[colg];
#pragma unroll
    for (int i = 0; i < 4; ++i) {
      int rbase = m0 + wm + i * 16 + (l >> 4) * 4;
#pragma unroll
      for (int reg = 0; reg < 4; ++reg) {
        int gm = rbase + reg;
        if (gm >= N_NODES) continue;
        C[(size_t)gm * 128 + colg] = acc[i][j][reg] + bj;
      }
    }
  }
}

// ---------- batch-norm ----------
__global__ __launch_bounds__(256) void k_bnstats(const float* __restrict__ h,
                                                 double* __restrict__ stats) {
  int c = threadIdx.x & 127;
  int half = threadIdx.x >> 7;
  double s = 0.0, sq = 0.0;
  for (int row = blockIdx.x * 2 + half; row < N_NODES; row += gridDim.x * 2) {
    float v = h[(size_t)row * K_DIM + c];
    s += v;
    sq += (double)v * v;
  }
  __shared__ double sh[256];
  sh[threadIdx.x] = s;
  __syncthreads();
  if (half == 0) atomicAdd(&stats[c], s + sh[threadIdx.x + 128]);
  __syncthreads();
  sh[threadIdx.x] = sq;
  __syncthreads();
  if (half == 0) atomicAdd(&stats[128 + c], sq + sh[threadIdx.x + 128]);
}

__global__ void k_bnfin(const double* __restrict__ stats,
                        const float* __restrict__ normparams,
                        float* __restrict__ fstats) {
  int c = threadIdx.x;
  double s = stats[c], sq = stats[128 + c];
  double mean = s / N_NODES;
  double var = (sq - mean * mean * N_NODES) / (N_NODES - 1);
  float gamma = normparams[0];
  fstats[c] = (float)mean;
  fstats[128 + c] = (float)((double)gamma / sqrt(var + EPS));
}

__global__ __launch_bounds__(256) void k_bnapply(
    float* __restrict__ h, const float* __restrict__ fstats,
    const float* __restrict__ normparams) {
  int idx = blockIdx.x * 256 + threadIdx.x;
  if (idx >= N_NODES * 32) return;
  float beta = normparams[1];
  float4 v = ((float4*)h)[idx];
  int c4 = (idx & 31) * 4;
  v.x = (v.x - fstats[c4 + 0]) * fstats[128 + c4 + 0] + beta;
  v.y = (v.y - fstats[c4 + 1]) * fstats[128 + c4 + 1] + beta;
  v.z = (v.z - fstats[c4 + 2]) * fstats[128 + c4 + 2] + beta;
  v.w = (v.w - fstats[c4 + 3]) * fstats[128 + c4 + 3] + beta;
  ((float4*)h)[idx] = v;
}

extern "C" void kernel_launch(void* const* d_in, const int* in_sizes, int n_in,
                              void* d_out, int out_size, void* d_ws, size_t ws_size,
                              hipStream_t stream) {
  (void)in_sizes; (void)n_in; (void)out_size; (void)ws_size;
  const float* nodes = (const float*)d_in[0];
  const float* rels = (const float*)d_in[1];
  const float* W1 = (const float*)d_in[2];
  const float* b1 = (const float*)d_in[3];
  const float* W2 = (const float*)d_in[4];
  const float* b2 = (const float*)d_in[5];
  const float* normparams = (const float*)d_in[6];
  const int* froms = (const int*)d_in[7];
  const int* tos = (const int*)d_in[8];
  const int* relidx = (const int*)d_in[9];
  float* out = (float*)d_out;
  char* ws = (char*)d_ws;
  char* dob = (char*)d_out;

  // ---- ws layout (102,763,520 B, well under proven tier) ----
  unsigned short* Aimg = (unsigned short*)ws;                 // 51,249,152 (391*16*8192)
  unsigned short* h1img = (unsigned short*)(ws + 51249152);   // 51,249,152
  unsigned short* W2s = (unsigned short*)(ws + 102498304);    //     262,144
  double* stats = (double*)(ws + 102760448);                  //       2,048
  float* fstats = (float*)(ws + 102762496);                   //       1,024

  // ---- d_out scratch (all dead before GEMM2 overwrites d_out) ----
  // cursor has its OWN region — denom stays live through the gathers (R8/R9 bug).
  unsigned short* W1s = (unsigned short*)dob;          // @0: 2,097,152
  int* row_ptr = (int*)(dob + 2097152);                // 1,600,004
  int* edge_order = (int*)(dob + 3700000);             // 2,000,000
  int* count = (int*)(dob + 5700000);                  // 1,600,000
  int* aux = (int*)(dob + 7300000);                    //     6,252
  float* denom = (float*)(dob + 7310000);              // 1,600,000 (LIVE thru gathers)
  unsigned* rowmax = (unsigned*)(dob + 8910000);       // 1,600,000
  float* att = (float*)(dob + 10510000);               // 2,000,000 (att -> ex)
  int* cursor = (int*)(dob + 12510000);                // 1,600,000 (own region)

  hipMemsetAsync(dob + 7310000, 0, 3200000, stream);   // denom + rowmax
  hipMemsetAsync(dob + 5700000, 0, 1600000, stream);   // count
  hipMemsetAsync(ws + 102760448, 0, 2048, stream);     // stats

  // edge pipeline
  k_edge_att<<<E_EDGES / 8, 256, 0, stream>>>(nodes, rels, froms, tos, relidx,
                                              att, rowmax);
  k_edge_exp_cnt<<<(E_EDGES + 255) / 256, 256, 0, stream>>>(froms, relidx,
                                                            rowmax, att, denom,
                                                            count);

  // CSR build
  k_scan1<<<SCAN_BLOCKS, 256, 0, stream>>>(count, aux);
  k_scan2<<<1, 256, 0, stream>>>(aux);
  k_scan3<<<SCAN_BLOCKS, 256, 0, stream>>>(count, aux, row_ptr, cursor);
  k_fill<<<(E_EDGES + 255) / 256, 256, 0, stream>>>(froms, relidx, cursor,
                                                    edge_order);

  // weight images (split bf16 kept for W1/W2)
  k_prep_w<<<256, 256, 0, stream>>>(W1, W1s, 512, 4, 7);
  k_prep_w<<<32, 256, 0, stream>>>(W2, W2s, 128, 1, 6);

  // two relation batches of 4: gather (div fused) -> pipelined GEMM1
  for (int b = 0; b < 2; ++b) {
    k_gather_bf<<<25024, 256, 0, stream>>>(nodes, tos, att, denom, row_ptr,
                                           edge_order, b * 4, Aimg);
    const unsigned short* Bimg = W1s + (size_t)b * 524288;
    if (b == 0)
      k_gemm1<0><<<1564, 256, 0, stream>>>(Aimg, Bimg, b1, h1img);
    else
      k_gemm1<2><<<1564, 256, 0, stream>>>(Aimg, Bimg, b1, h1img);
  }

  // GEMM2: out = h1 @ W2 + b2 (overwrites all d_out scratch)
  k_gemm2<<<391, 256, 0, stream>>>(h1img, W2s, b2, out);

  k_bnstats<<<256, 256, 0, stream>>>(out, stats);
  k_bnfin<<<1, 128, 0, stream>>>(stats, normparams, fstats);
  k_bnapply<<<(N_NODES * 32 + 255) / 256, 256, 0, stream>>>(out, fstats,
                                                            normparams);
}